// Round 12
// baseline (2934.328 us; speedup 1.0000x reference)
//
#include <hip/hip_runtime.h>

__device__ __forceinline__ float lrelu(float v){ return v >= 0.f ? v : 0.1f*v; }

// Dims: B=4, C=64, H=W=160, HW=25600, per-tensor (B,64,160,160) f32: batch stride 1,638,400
// ws: 4 f32 slots x 26,214,400 B (A, Bv, T1, T2) + part/Weff tail. branchH lives in d_out.
// Per iter: permV A->D (A^T), epiV(D)->T2, spa->T1, permV T2->Bv, ang->T2, epiH->D,
//           red, attW, fuse1->T1(inplace), fuse2->A (or dout), permM A->Bv.
// XCD swizzle: P = ((tsel*NC + cog) << 3) | xcd -> cogroups of a tile temporally adjacent.
// R5: BK=2 with 10 scalar-gather loads in flight regressed (VGPR 60, deep VMEM queue).
// R7: float4-halo staging -> conflicts 0. R10: epi window-split. Best 2780.
// R11: LDS tap-read reduction was NULL -> stall is barrier+VMEM-drain cadence, not LDS issue.
// R12: BK=2 retry with float4-halo staging (R5 mechanism removed): 4 planes, 32 barriers,
//      288 FMA per barrier covers prefetch latency; only 2-4 float4 loads in flight.

// ---------------- spa: per-view 3x3 conv (zero pad at view edges) ----------
// 16-row half-views, double-buffered LDS, one barrier per ci, 8 co per block.
// Pixel pair (2q, 2q+1): taps = plane rows 2q..2q+3 x cols c+3..c+5 (12 dwords, mergeable).
// grid: 1600 1-D swizzled (200 tiles x 8 cogroups of 8co).
__global__ __launch_bounds__(256) void k_spa(const float* __restrict__ buf1, const float* __restrict__ w,
                                             float* __restrict__ out){
  const int P = blockIdx.x;
  const int within = P >> 3, cog = within & 7, tsel = within >> 3;
  const int tg = (P & 7)*25 + tsel;            // 0..199
  const int b = tg / 50, r2 = tg % 50;
  const int view = r2 >> 1, half = r2 & 1;
  const int bi = view / 5, bj = view % 5;
  const int th0 = half*16;
  const int tid = threadIdx.x;
  __shared__ float plane[2][18*38];   // plane row rr = view row th0-1+rr; data cols 4..35, zeros at 3/36
  for (int idx=tid; idx<2*18*38; idx+=256) ((float*)plane)[idx]=0.f;
  float acc[2][8];
  #pragma unroll
  for (int k=0;k<2;k++)
    #pragma unroll
    for (int c=0;c<8;c++) acc[k][c]=0.f;
  const float* src = buf1 + (size_t)b*1638400 + bi*32*160 + bj*32;
  const float* wb = w + (size_t)(cog*8)*576;   // [co][ci][9]
  const int sr = tid >> 3, sq = (tid & 7)*4;   // staging: 18 rows x 8 float4
  const int vr = th0 - 1 + sr;
  const bool rowok = (tid < 144) && ((unsigned)vr < 32u);
  __syncthreads();                              // zero-init visible before staging
  if (rowok)
    *(float4*)&plane[0][sr*38 + 4 + sq] = *(const float4*)(src + vr*160 + sq);
  __syncthreads();
  const int lr2 = tid >> 5, c = tid & 31;      // pixel rows 2*lr2, 2*lr2+1
  for (int ci=0; ci<64; ci++){
    // issue next-ci loads early (latency hides under FMA block)
    float4 nx;
    const bool ld = rowok && (ci < 63);
    if (ld) nx = *(const float4*)(src + (size_t)(ci+1)*25600 + vr*160 + sq);
    const float* P2 = plane[ci & 1];
    float g[4][3];
    {
      const float* pp = &P2[(2*lr2)*38 + c + 3];
      g[0][0]=pp[0];   g[0][1]=pp[1];   g[0][2]=pp[2];
      g[1][0]=pp[38];  g[1][1]=pp[39];  g[1][2]=pp[40];
      g[2][0]=pp[76];  g[2][1]=pp[77];  g[2][2]=pp[78];
      g[3][0]=pp[114]; g[3][1]=pp[115]; g[3][2]=pp[116];
    }
    #pragma unroll
    for (int co=0;co<8;co++){
      const float* wp = wb + (size_t)co*576 + ci*9;   // uniform -> s_load
      float w0=wp[0],w1=wp[1],w2=wp[2],w3=wp[3],w4=wp[4],w5=wp[5],w6=wp[6],w7=wp[7],w8=wp[8];
      acc[0][co] += g[0][0]*w0+g[0][1]*w1+g[0][2]*w2+g[1][0]*w3+g[1][1]*w4
                  + g[1][2]*w5+g[2][0]*w6+g[2][1]*w7+g[2][2]*w8;
      acc[1][co] += g[1][0]*w0+g[1][1]*w1+g[1][2]*w2+g[2][0]*w3+g[2][1]*w4
                  + g[2][2]*w5+g[3][0]*w6+g[3][1]*w7+g[3][2]*w8;
    }
    if (ld) *(float4*)&plane[(ci+1)&1][sr*38 + 4 + sq] = nx;
    __syncthreads();
  }
  #pragma unroll
  for (int k=0;k<2;k++){
    int si = th0 + 2*lr2 + k;
    int h = si*5 + bi, wq = c*5 + bj;
    #pragma unroll
    for (int co=0;co<8;co++){
      int ch = b*64 + cog*8 + co;
      out[(size_t)ch*25600 + h*160 + wq] = lrelu(acc[k][co]);
    }
  }
}

// ---------------- ang: per-macropixel (5x5) 3x3 conv, row-per-thread ------
// Block (b, mip) covers image rows mip*10..mip*10+9 (2 macropixel rows, 1600 px).
// 320 threads: u=tid>>6 (wave-uniform), mi_l=(tid>>5)&1, mp=tid&31.
// LDS: plain rows, stride 164 -> staging writes LINEAR float4; reads stride-5 scalar
// (5 coprime 32 -> conflict-free). Guard rows 0,6 zero.
// grid: 1024 1-D swizzled (64 tiles x 16 cogroups of 4co).
__global__ __launch_bounds__(320) void k_ang(const float* __restrict__ bufA, const float* __restrict__ w,
                                             float* __restrict__ out){
  const int P = blockIdx.x;
  const int within = P >> 3, cog = within & 15, tsel = within >> 4;
  const int tg = (P & 7)*8 + tsel;             // 0..63
  const int b = tg >> 4, mip = tg & 15;
  const int tid = threadIdx.x;
  // per-buffer floats: [mi][7][164] = 2296
  __shared__ float lds[2][2296];
  for (int i=tid; i<2*2296; i+=320) ((float*)lds)[i] = 0.f;

  const int u = tid >> 6, mi_l = (tid >> 5) & 1, mp = tid & 31;
  int ro[3];
  #pragma unroll
  for (int du=0; du<3; du++)
    ro[du] = mi_l*1148 + (u+du)*164 + mp*5;    // tap row = 1+(u-1)+du = u+du
  // staging: 400 float4 slots (10 rows x 40); s0 = tid (rows 0..7), s1 = tid+320 (tid<80, rows 8,9)
  const bool st1 = tid < 80;
  const int rr0 = tid/40,       q0 = tid%40;
  const int rr1 = (tid+320)/40, q1 = (tid+320)%40;
  const int dst0 = (rr0/5)*1148 + (1 + rr0%5)*164 + q0*4;
  const int dst1 = (rr1/5)*1148 + (1 + rr1%5)*164 + q1*4;
  const float* src = bufA + (size_t)b*1638400 + (size_t)(mip*10)*160;
  const float* wb = w + (size_t)(cog*4)*576;

  float acc[4][5];
  #pragma unroll
  for (int co=0;co<4;co++)
    #pragma unroll
    for (int v=0;v<5;v++) acc[co][v]=0.f;

  __syncthreads();                       // zero-init visible
  {
    *(float4*)&lds[0][dst0] = *(const float4*)(src + rr0*160 + q0*4);
    if (st1)
      *(float4*)&lds[0][dst1] = *(const float4*)(src + rr1*160 + q1*4);
  }
  __syncthreads();
  for (int ci=0; ci<64; ci++){
    float4 n0, n1;
    if (ci < 63){
      n0 = *(const float4*)(src + (size_t)(ci+1)*25600 + rr0*160 + q0*4);
      if (st1) n1 = *(const float4*)(src + (size_t)(ci+1)*25600 + rr1*160 + q1*4);
    }
    const float* Pb = lds[ci & 1];
    float c[3][5];
    #pragma unroll
    for (int du=0;du<3;du++){
      const float* rp = &Pb[ro[du]];
      c[du][0]=rp[0]; c[du][1]=rp[1]; c[du][2]=rp[2]; c[du][3]=rp[3]; c[du][4]=rp[4];
    }
    #pragma unroll
    for (int co=0;co<4;co++){
      const float* wp = wb + (size_t)co*576 + ci*9;   // uniform -> s_load
      float w0=wp[0],w1=wp[1],w2=wp[2],w3=wp[3],w4=wp[4],w5=wp[5],w6=wp[6],w7=wp[7],w8=wp[8];
      acc[co][0] += c[0][0]*w1 + c[0][1]*w2
                  + c[1][0]*w4 + c[1][1]*w5
                  + c[2][0]*w7 + c[2][1]*w8;
      acc[co][1] += c[0][0]*w0 + c[0][1]*w1 + c[0][2]*w2
                  + c[1][0]*w3 + c[1][1]*w4 + c[1][2]*w5
                  + c[2][0]*w6 + c[2][1]*w7 + c[2][2]*w8;
      acc[co][2] += c[0][1]*w0 + c[0][2]*w1 + c[0][3]*w2
                  + c[1][1]*w3 + c[1][2]*w4 + c[1][3]*w5
                  + c[2][1]*w6 + c[2][2]*w7 + c[2][3]*w8;
      acc[co][3] += c[0][2]*w0 + c[0][3]*w1 + c[0][4]*w2
                  + c[1][2]*w3 + c[1][3]*w4 + c[1][4]*w5
                  + c[2][2]*w6 + c[2][3]*w7 + c[2][4]*w8;
      acc[co][4] += c[0][3]*w0 + c[0][4]*w1
                  + c[1][3]*w3 + c[1][4]*w4
                  + c[2][3]*w6 + c[2][4]*w7;
    }
    if (ci < 63){
      float* Q = lds[(ci+1)&1];
      *(float4*)&Q[dst0] = n0;
      if (st1) *(float4*)&Q[dst1] = n1;
    }
    __syncthreads();
  }
  const int h = (mip*2 + mi_l)*5 + u;
  const int wc0 = mp*5;
  #pragma unroll
  for (int co=0;co<4;co++){
    int ch = b*64 + cog*4 + co;
    float* op = out + (size_t)ch*25600 + (size_t)h*160 + wc0;
    op[0]=lrelu(acc[co][0]); op[1]=lrelu(acc[co][1]); op[2]=lrelu(acc[co][2]);
    op[3]=lrelu(acc[co][3]); op[4]=lrelu(acc[co][4]);
  }
}

// ---------------- fused EPI: [1,15]s5p5 + lrelu + 1x1 64->320 + shuffle ---
// Window-split: block = (b, hw, half); handles 16 of 32 windows. Local tap idx
// 3 + wvl*5 + t in [3,93); stage x in [80h-8, 80h+88) -> rowp[64][96] (28KB total).
// y2s stride 84. grid 1280 (= B*160*2), 320 threads.
__global__ __launch_bounds__(320) void k_epi(const float* __restrict__ bufA, const float* __restrict__ we1,
                                             const float* __restrict__ we2, float* __restrict__ out){
  const int bb = blockIdx.x >> 1, half = blockIdx.x & 1;
  const int b = bb / 160, hw = bb % 160;
  const int tid = threadIdx.x;
  __shared__ float rowp[64*96];    // per-ci 96 cols; reused as y2s (64 x 84)
  __shared__ float y1s[64*16];
  // stage: 22 float4 per ci (88 valid floats) + 8 zero cols
  const int lofs = half ? 0 : 8;   // local col of first staged float
  const int xofs = half ? 72 : 0;  // global x of first staged float
  for (int ft=tid; ft<1408; ft+=320){
    int ci = ft/22, q = ft - ci*22;
    *(float4*)&rowp[ci*96 + lofs + q*4] =
      *(const float4*)(bufA + (size_t)b*1638400 + (size_t)ci*25600 + (size_t)hw*160 + xofs + q*4);
  }
  for (int idx=tid; idx<512; idx+=320){
    int ci = idx>>3, j = idx&7;
    rowp[ci*96 + (half ? 88+j : j)] = 0.f;
  }
  __syncthreads();
  // conv1: 4 windows per thread (256 active). taps at local idx 3 + wvl*5 + t.
  if (tid < 256){
    const int co = tid >> 2, wvl0 = (tid & 3)*4;
    const int a0 = 2 + wvl0*5;                // even -> float2-aligned
    float acc[4];
    #pragma unroll
    for (int j=0;j<4;j++) acc[j]=0.f;
    const float* wp0 = we1 + (size_t)co*960;
    for (int ci=0; ci<64; ci++){
      float fl[32];
      const float* rp = &rowp[ci*96 + a0];
      #pragma unroll
      for (int m=0;m<16;m++) *(float2*)&fl[2*m] = *(const float2*)&rp[2*m];
      const float* wp = wp0 + ci*15;
      #pragma unroll
      for (int t=0;t<15;t++){
        float wt = wp[t];
        #pragma unroll
        for (int j=0;j<4;j++) acc[j] += fl[1 + j*5 + t]*wt;
      }
    }
    #pragma unroll
    for (int j=0;j<4;j++) y1s[co*16 + wvl0 + j] = lrelu(acc[j]);
  }
  __syncthreads();
  // conv2 1x1 64->320 over 16 windows; shuffle into y2s[c*84 + wvl*5 + kk]
  {
    const int oc = tid, kk = oc >> 6, c = oc & 63;
    float a2[16];
    #pragma unroll
    for (int wv=0;wv<16;wv++) a2[wv]=0.f;
    const float* wp = we2 + (size_t)oc*64;
    for (int ci=0; ci<64; ci++){
      float wt = wp[ci];
      const float* yp = &y1s[ci*16];
      #pragma unroll
      for (int wv=0; wv<16; wv++) a2[wv] += yp[wv]*wt;
    }
    float* y2s = rowp;
    #pragma unroll
    for (int wv=0; wv<16; wv++) y2s[c*84 + wv*5 + kk] = lrelu(a2[wv]);
  }
  __syncthreads();
  // coalesced writeout: 80 floats per channel at w-range [half*80, half*80+80)
  {
    const float* y2s = rowp;
    for (int k=0;k<4;k++){
      int f = (tid + k*320)*4;               // < 5120
      int c = f/80, rr = f - c*80;
      *(float4*)(out + (size_t)(b*64+c)*25600 + (size_t)hw*160 + half*80 + rr)
        = *(const float4*)&y2s[c*84+rr];
    }
  }
}

// ---------------- permV: per-(b,c) 160x160 transpose src[i][j] -> dst[j][i]
__global__ __launch_bounds__(256) void k_permV(const float* __restrict__ tmp, float* __restrict__ dst){
  const int bc = blockIdx.x;
  const int ti = blockIdx.y / 5, tj = blockIdx.y % 5;
  const int hw0 = ti*32, r0 = tj*32;
  const int lx = threadIdx.x & 31, ly = threadIdx.x >> 5;   // 32 x 8
  __shared__ float tile[32][33];
  const float* in = tmp + (size_t)bc*25600;
  float* outp = dst + (size_t)bc*25600;
  for (int yy=ly; yy<32; yy+=8)
    tile[yy][lx] = in[(size_t)(hw0+yy)*160 + r0 + lx];
  __syncthreads();
  for (int yy=ly; yy<32; yy+=8)
    outp[(size_t)(r0+yy)*160 + hw0 + lx] = tile[lx][yy];
}

// ---------------- permM: mac2sai  newB1[f] = A[ai*32+hh][aj*32+ww], f=hh*800+ww*25+ai*5+aj
__global__ __launch_bounds__(256) void k_permM(const float* __restrict__ A, float* __restrict__ dst){
  const int bc = blockIdx.x >> 5, hh = blockIdx.x & 31;
  const int tid = threadIdx.x;
  __shared__ float rows[5*160];
  const float* in = A + (size_t)bc*25600;
  if (tid < 200){
    int ai = tid/40, q = (tid - ai*40)*4;
    *(float4*)&rows[ai*160 + q] = *(const float4*)(in + (size_t)(ai*32+hh)*160 + q);
  }
  __syncthreads();
  float* outp = dst + (size_t)bc*25600 + (size_t)hh*800;
  for (int t=tid; t<800; t+=256){
    int ww = t/25, r2 = t - ww*25, ai = r2/5, aj = r2 - ai*5;
    outp[t] = rows[ai*160 + aj*32 + ww];
  }
}

// ---------------- single-pass stats: 4 sums + 10 products (E-formula) -----
__global__ __launch_bounds__(256) void k_red(const float* __restrict__ b0, const float* __restrict__ b1,
                                             const float* __restrict__ b2, const float* __restrict__ b3,
                                             float* __restrict__ part){
  const int b = blockIdx.y, blk = blockIdx.x;
  const int tid = threadIdx.x;
  const size_t off = (size_t)b*1638400 + (size_t)blk*25600;
  float s0=0,s1=0,s2=0,s3=0;
  float p00=0,p01=0,p02=0,p03=0,p11=0,p12=0,p13=0,p22=0,p23=0,p33=0;
  for (int it=0; it<25; it++){
    size_t m = off + it*1024 + tid*4;
    float4 x0 = *(const float4*)(b0+m);
    float4 x1 = *(const float4*)(b1+m);
    float4 x2 = *(const float4*)(b2+m);
    float4 x3 = *(const float4*)(b3+m);
    s0 += (x0.x+x0.y)+(x0.z+x0.w);
    s1 += (x1.x+x1.y)+(x1.z+x1.w);
    s2 += (x2.x+x2.y)+(x2.z+x2.w);
    s3 += (x3.x+x3.y)+(x3.z+x3.w);
    p00 += x0.x*x0.x+x0.y*x0.y+x0.z*x0.z+x0.w*x0.w;
    p01 += x0.x*x1.x+x0.y*x1.y+x0.z*x1.z+x0.w*x1.w;
    p02 += x0.x*x2.x+x0.y*x2.y+x0.z*x2.z+x0.w*x2.w;
    p03 += x0.x*x3.x+x0.y*x3.y+x0.z*x3.z+x0.w*x3.w;
    p11 += x1.x*x1.x+x1.y*x1.y+x1.z*x1.z+x1.w*x1.w;
    p12 += x1.x*x2.x+x1.y*x2.y+x1.z*x2.z+x1.w*x2.w;
    p13 += x1.x*x3.x+x1.y*x3.y+x1.z*x3.z+x1.w*x3.w;
    p22 += x2.x*x2.x+x2.y*x2.y+x2.z*x2.z+x2.w*x2.w;
    p23 += x2.x*x3.x+x2.y*x3.y+x2.z*x3.z+x2.w*x3.w;
    p33 += x3.x*x3.x+x3.y*x3.y+x3.z*x3.z+x3.w*x3.w;
  }
  float vals[14] = {s0,s1,s2,s3,p00,p01,p02,p03,p11,p12,p13,p22,p23,p33};
  __shared__ float red[4][14];
  int lane = tid & 63, wv = tid >> 6;
  #pragma unroll
  for (int j=0;j<14;j++){
    float v = vals[j];
    #pragma unroll
    for (int o=32;o>0;o>>=1) v += __shfl_down(v,o,64);
    if (lane==0) red[wv][j]=v;
  }
  __syncthreads();
  if (tid<14) part[((size_t)b*64+blk)*16 + tid] = red[0][tid]+red[1][tid]+red[2][tid]+red[3][tid];
}

// ---- att (4x4) via E-formula, fold attention + identity into fuse1 weights
__global__ __launch_bounds__(256) void k_attW(const float* __restrict__ part,
        const float* __restrict__ alpha, const float* __restrict__ gamma, const float* __restrict__ beta,
        int iblk, const float* __restrict__ wf1, float* __restrict__ Weff){
  const int b = blockIdx.x, tid = threadIdx.x;
  __shared__ float st[14];
  __shared__ float att[16];
  if (tid<14){
    float t=0;
    for (int blk=0;blk<64;blk++) t += part[((size_t)b*64+blk)*16 + tid];
    st[tid]=t;
  }
  __syncthreads();
  if (tid==0){
    const float M = 1638400.f;
    float s[4] = {st[0],st[1],st[2],st[3]};
    float S[4][4];
    S[0][0]=st[4];  S[0][1]=S[1][0]=st[5];  S[0][2]=S[2][0]=st[6];  S[0][3]=S[3][0]=st[7];
    S[1][1]=st[8];  S[1][2]=S[2][1]=st[9];  S[1][3]=S[3][1]=st[10];
    S[2][2]=st[11]; S[2][3]=S[3][2]=st[12]; S[3][3]=st[13];
    float al=alpha[iblk], ga=gamma[iblk], be=beta[iblk];
    float scale = al/(M-1.f);
    float cov[4][4], ss=0.f;
    for (int n=0;n<4;n++) for (int k=0;k<4;k++){
      float c = (S[n][k] - s[n]*s[k]/M)*scale;
      cov[n][k]=c; ss += c*c;
    }
    float rms = sqrtf(ss/16.f + 1e-5f);
    for (int n=0;n<4;n++) for (int k=0;k<4;k++){
      float g = ga*cov[n][k]/rms + be;
      att[n*4+k] = g/(1.f+expf(-g));
    }
  }
  __syncthreads();
  for (int idx=tid; idx<16384; idx+=256){
    int co=idx>>8, kc=idx&255, k=kc>>6, c=kc&63;
    float v = wf1[co*256+kc];
    #pragma unroll
    for (int n=0;n<4;n++) v += att[n*4+k]*wf1[co*256+n*64+c];
    Weff[(size_t)b*16384+idx] = v;
  }
}

// ---------------- fuse1: per-batch GEMM 64x256 @ 256x25600, float4-blocked
__global__ __launch_bounds__(256) void k_fuse1(const float* b0, const float* __restrict__ b1,
                                               const float* __restrict__ b2, const float* __restrict__ b3,
                                               const float* __restrict__ Weff, float* y64){
  const int tile = blockIdx.x, b = blockIdx.y;
  const int px0 = tile*64;
  const int tid = threadIdx.x;
  const int ti = tid >> 4, tj = tid & 15;      // co = ti*4.., px = tj*4..
  __shared__ float xs[64][68];                 // [k2][px]
  __shared__ float wt[64][68];                 // [k2][co]
  float acc[4][4];
  #pragma unroll
  for (int i=0;i<4;i++)
    #pragma unroll
    for (int j=0;j<4;j++) acc[i][j]=0.f;
  const float* bptr[4] = {b0,b1,b2,b3};
  for (int kb=0; kb<4; kb++){
    const float* xbk = bptr[kb] + (size_t)b*1638400 + px0;
    const float* wb = Weff + (size_t)b*16384 + kb*64;
    __syncthreads();
    for (int idx=tid; idx<4096; idx+=256){
      int kc=idx>>6, px=idx&63;
      xs[kc][px] = xbk[(size_t)kc*25600 + px];
    }
    for (int idx=tid; idx<4096; idx+=256){
      int co=idx>>6, k2=idx&63;
      wt[k2][co] = wb[co*256 + k2];
    }
    __syncthreads();
    for (int k2=0;k2<64;k2++){
      float4 a = *(const float4*)&wt[k2][ti*4];
      float4 v = *(const float4*)&xs[k2][tj*4];
      acc[0][0]+=a.x*v.x; acc[0][1]+=a.x*v.y; acc[0][2]+=a.x*v.z; acc[0][3]+=a.x*v.w;
      acc[1][0]+=a.y*v.x; acc[1][1]+=a.y*v.y; acc[1][2]+=a.y*v.z; acc[1][3]+=a.y*v.w;
      acc[2][0]+=a.z*v.x; acc[2][1]+=a.z*v.y; acc[2][2]+=a.z*v.z; acc[2][3]+=a.z*v.w;
      acc[3][0]+=a.w*v.x; acc[3][1]+=a.w*v.y; acc[3][2]+=a.w*v.z; acc[3][3]+=a.w*v.w;
    }
  }
  #pragma unroll
  for (int i=0;i<4;i++){
    int co = ti*4 + i;
    float4 o = make_float4(lrelu(acc[i][0]), lrelu(acc[i][1]), lrelu(acc[i][2]), lrelu(acc[i][3]));
    *(float4*)(y64 + ((size_t)(b*64+co))*25600 + px0 + tj*4) = o;
  }
}

// ---------------- fuse2: dilated 3x3 (dil 5, pad 5) + residual ------------
// 16x32 tiles, BK=2 with float4-halo staging: 4 planes of 26x48 (20KB), 2 ci per
// barrier (288 FMA/barrier, 32 barriers), only 2-4 float4 loads in flight per thread.
// grid: 1600 1-D swizzled (200 tiles x 8 cogroups of 8co).
template<int FINAL>
__global__ __launch_bounds__(256) void k_fuse2(const float* __restrict__ y64, const float* resid,
                                               const float* __restrict__ w, float* outp){
  const int P = blockIdx.x;
  const int within = P >> 3, cog = within & 7, tsel = within >> 3;
  const int tg = (P & 7)*25 + tsel;            // 0..199
  const int b = tg / 50, tile = tg % 50;
  const int th0 = (tile/5)*16, tw0 = (tile%5)*32;
  const int tid = threadIdx.x;
  __shared__ float plane[4][26*48];   // plane row r = global row th0-5+r; col cc = global col tw0-8+cc
  float acc[2][8];
  #pragma unroll
  for (int k=0;k<2;k++)
    #pragma unroll
    for (int c=0;c<8;c++) acc[k][c]=0.f;
  const float* src = y64 + (size_t)b*1638400;
  const float* wb = w + (size_t)(cog*8)*576;
  // staging: 26 rows x 12 float4 = 312 slots; slot tid always, slot tid+256 iff tid<56
  const int s0r = tid/12,        s0c = tid - (tid/12)*12;
  const int s1i = tid + 256;
  const int s1r = s1i/12,        s1c = s1i - (s1i/12)*12;
  const bool has1 = tid < 56;
  const int g0h = th0 - 5 + s0r, g0w = tw0 - 8 + s0c*4;
  const int g1h = th0 - 5 + s1r, g1w = tw0 - 8 + s1c*4;
  const bool v0 = ((unsigned)g0h < 160u) && ((unsigned)g0w < 160u);
  const bool v1 = has1 && ((unsigned)g1h < 160u) && ((unsigned)g1w < 160u);
  const int go0 = g0h*160 + g0w, go1 = g1h*160 + g1w;
  const int d0 = s0r*48 + s0c*4, d1 = s1r*48 + s1c*4;
  const float4 z4 = make_float4(0.f,0.f,0.f,0.f);
  // prologue: stage ci=0 -> plane0, ci=1 -> plane1 (OOB groups -> zero = implicit pad)
  {
    float4 x0 = v0 ? *(const float4*)(src + go0) : z4;
    float4 y0 = v0 ? *(const float4*)(src + 25600 + go0) : z4;
    *(float4*)&plane[0][d0] = x0;
    *(float4*)&plane[1][d0] = y0;
    if (has1){
      float4 x1 = v1 ? *(const float4*)(src + go1) : z4;
      float4 y1 = v1 ? *(const float4*)(src + 25600 + go1) : z4;
      *(float4*)&plane[0][d1] = x1;
      *(float4*)&plane[1][d1] = y1;
    }
  }
  __syncthreads();
  const int lr = tid >> 5, c = tid & 31;
  const int tap = lr*48 + c + 3;
  for (int t=0; t<32; t++){
    const int pp = (t & 1) << 1;               // planes pp, pp+1 hold ci=2t, 2t+1
    // issue next-pair loads early (2-4 clean float4s in flight)
    float4 n0a, n0b, n1a, n1b;
    if (t < 31){
      const float* sA = src + (size_t)(2*t+2)*25600;
      const float* sB = sA + 25600;
      n0a = v0 ? *(const float4*)(sA + go0) : z4;
      n0b = v0 ? *(const float4*)(sB + go0) : z4;
      if (has1){
        n1a = v1 ? *(const float4*)(sA + go1) : z4;
        n1b = v1 ? *(const float4*)(sB + go1) : z4;
      }
    }
    #pragma unroll
    for (int h2=0; h2<2; h2++){
      const int ci = 2*t + h2;
      const float* Pb = plane[pp + h2];
      float t0[9], t1[9];
      {
        const float* pq = &Pb[tap];
        t0[0]=pq[0];      t0[1]=pq[5];      t0[2]=pq[10];
        t0[3]=pq[240];    t0[4]=pq[245];    t0[5]=pq[250];
        t0[6]=pq[480];    t0[7]=pq[485];    t0[8]=pq[490];
        const float* qq = pq + 8*48;
        t1[0]=qq[0];      t1[1]=qq[5];      t1[2]=qq[10];
        t1[3]=qq[240];    t1[4]=qq[245];    t1[5]=qq[250];
        t1[6]=qq[480];    t1[7]=qq[485];    t1[8]=qq[490];
      }
      #pragma unroll
      for (int co=0;co<8;co++){
        const float* wp = wb + (size_t)co*576 + ci*9;
        float w0=wp[0],w1=wp[1],w2=wp[2],w3=wp[3],w4=wp[4],w5=wp[5],w6=wp[6],w7=wp[7],w8=wp[8];
        acc[0][co] += t0[0]*w0+t0[1]*w1+t0[2]*w2+t0[3]*w3+t0[4]*w4
                    + t0[5]*w5+t0[6]*w6+t0[7]*w7+t0[8]*w8;
        acc[1][co] += t1[0]*w0+t1[1]*w1+t1[2]*w2+t1[3]*w3+t1[4]*w4
                    + t1[5]*w5+t1[6]*w6+t1[7]*w7+t1[8]*w8;
      }
    }
    if (t < 31){
      float* QA = plane[pp ^ 2];
      float* QB = plane[(pp ^ 2) + 1];
      *(float4*)&QA[d0] = n0a;
      *(float4*)&QB[d0] = n0b;
      if (has1){
        *(float4*)&QA[d1] = n1a;
        *(float4*)&QB[d1] = n1b;
      }
    }
    __syncthreads();
  }
  #pragma unroll
  for (int k=0;k<2;k++){
    int h = th0 + lr + k*8, wq = tw0 + c;
    #pragma unroll
    for (int co=0;co<8;co++){
      int cg = cog*8 + co;
      size_t base = ((size_t)(b*64+cg)*160 + h)*160 + wq;
      outp[base] = acc[k][co] + resid[base];
    }
  }
}

extern "C" void kernel_launch(void* const* d_in, const int* in_sizes, int n_in,
                              void* d_out, int out_size, void* d_ws, size_t ws_size,
                              hipStream_t stream){
  const float* x    = (const float*)d_in[0];
  const float* x1   = (const float*)d_in[1];
  const float* wspa = (const float*)d_in[2];
  const float* wang = (const float*)d_in[3];
  const float* we1  = (const float*)d_in[4];
  const float* we2  = (const float*)d_in[5];
  const float* al   = (const float*)d_in[6];
  const float* ga   = (const float*)d_in[7];
  const float* be   = (const float*)d_in[8];
  const float* wf1  = (const float*)d_in[9];
  const float* wf2  = (const float*)d_in[10];

  char* ws = (char*)d_ws;
  const size_t SLOT = 26214400;
  float* A  = (float*)(ws);          // MacPI buf (in-place residual chain)
  float* Bv = (float*)(ws +   SLOT); // B1 input / branchV / newB1
  float* T1 = (float*)(ws + 2*SLOT); // branchSpa -> y64 in-place
  float* T2 = (float*)(ws + 3*SLOT); // epiV tmp -> branchAng
  float* part = (float*)(ws + 4*SLOT);            // 4*64*16 f32
  float* Weff = (float*)(ws + 4*SLOT + 16384);    // 4*64*256 f32
  float* D = (float*)d_out;          // A^T / branchH scratch; final output at the end

  for (int i=0;i<4;i++){
    const float* Asrc  = (i==0) ? x  : (const float*)A;
    const float* B1src = (i==0) ? x1 : (const float*)Bv;
    k_permV<<<dim3(256,25),256,0,stream>>>(Asrc, D);                             // D = Asrc^T
    k_epi<<<1280,320,0,stream>>>(D, we1 + (size_t)i*61440, we2 + (size_t)i*20480, T2);   // epiV (tmp layout)
    k_spa<<<1600,256,0,stream>>>(B1src, wspa + (size_t)i*36864, T1);
    k_permV<<<dim3(256,25),256,0,stream>>>(T2, Bv);                              // branchV
    k_ang<<<1024,320,0,stream>>>(Asrc, wang + (size_t)i*36864, T2);
    k_epi<<<1280,320,0,stream>>>(Asrc, we1 + (size_t)i*61440, we2 + (size_t)i*20480, D); // branchH
    k_red<<<dim3(64,4),256,0,stream>>>(T1, T2, D, Bv, part);
    k_attW<<<4,256,0,stream>>>(part, al, ga, be, i, wf1 + (size_t)i*16384, Weff);
    k_fuse1<<<dim3(400,4),256,0,stream>>>(T1, T2, D, Bv, Weff, T1);
    if (i<3){
      k_fuse2<0><<<1600,256,0,stream>>>(T1, Asrc, wf2 + (size_t)i*36864, A);
      k_permM<<<8192,256,0,stream>>>(A, Bv);
    } else {
      k_fuse2<1><<<1600,256,0,stream>>>(T1, Asrc, wf2 + (size_t)i*36864, D);
    }
  }
}

// Round 13
// 2806.934 us; speedup vs baseline: 1.0454x; 1.0454x over previous
//
#include <hip/hip_runtime.h>

__device__ __forceinline__ float lrelu(float v){ return v >= 0.f ? v : 0.1f*v; }

// Dims: B=4, C=64, H=W=160, HW=25600, per-tensor (B,64,160,160) f32: batch stride 1,638,400
// ws: 4 f32 slots x 26,214,400 B (A, Bv, T1, T2) + part/Weff/Wrep tail. branchH in d_out.
// Per iter: permV A->D (A^T), epiV(D)->T2, spa->T1, permV T2->Bv, ang->T2, epiH->D,
//           red, attW, fuse1->T1(inplace), fuse2->A (or dout), permM A->Bv.
// XCD swizzle: P = ((tsel*NC + cog) << 3) | xcd -> cogroups of a tile temporally adjacent.
// Lessons: BK=2 regresses under ALL staging forms (R5/R12). co=16 doubles weight
// dwords/FMA -> ~2x dur (R9): per-ci scalar weight fetch is the critical stream.
// R13: repack weights [co][ci][9] -> [ci][co][9] once per launch; per (ci,cog) the 72
// dwords are contiguous -> s_load_dwordx16 merging + sequential K$ lines.

// ---------------- weight repack: [4][64co][64ci][9] -> [4][64ci][64co][9], 3 tensors
__global__ __launch_bounds__(256) void k_wrep(const float* __restrict__ wspa, const float* __restrict__ wang,
                                              const float* __restrict__ wf2, float* __restrict__ outp){
  int id = blockIdx.x*256 + threadIdx.x;       // < 442368
  int t = id / 147456, r = id - t*147456;
  int i = r / 36864,  e = r - i*36864;
  int ci = e / 576,   r3 = e - ci*576;
  int co = r3 / 9,    j = r3 - co*9;
  const float* src = (t==0 ? wspa : (t==1 ? wang : wf2));
  outp[id] = src[(size_t)i*36864 + co*576 + ci*9 + j];
}

// ---------------- spa: per-view 3x3 conv (zero pad at view edges) ----------
// 16-row half-views, double-buffered LDS, one barrier per ci, 8 co per block.
// Pixel pair (2q, 2q+1): taps = plane rows 2q..2q+3 x cols c+3..c+5 (12 dwords).
// Weights pre-repacked: per ci, 72 contiguous dwords at ci*576 + cog*72.
// grid: 1600 1-D swizzled (200 tiles x 8 cogroups of 8co).
__global__ __launch_bounds__(256) void k_spa(const float* __restrict__ buf1, const float* __restrict__ w,
                                             float* __restrict__ out){
  const int P = blockIdx.x;
  const int within = P >> 3, cog = within & 7, tsel = within >> 3;
  const int tg = (P & 7)*25 + tsel;            // 0..199
  const int b = tg / 50, r2 = tg % 50;
  const int view = r2 >> 1, half = r2 & 1;
  const int bi = view / 5, bj = view % 5;
  const int th0 = half*16;
  const int tid = threadIdx.x;
  __shared__ float plane[2][18*38];   // plane row rr = view row th0-1+rr; data cols 4..35, zeros at 3/36
  for (int idx=tid; idx<2*18*38; idx+=256) ((float*)plane)[idx]=0.f;
  float acc[2][8];
  #pragma unroll
  for (int k=0;k<2;k++)
    #pragma unroll
    for (int c=0;c<8;c++) acc[k][c]=0.f;
  const float* src = buf1 + (size_t)b*1638400 + bi*32*160 + bj*32;
  const int sr = tid >> 3, sq = (tid & 7)*4;   // staging: 18 rows x 8 float4
  const int vr = th0 - 1 + sr;
  const bool rowok = (tid < 144) && ((unsigned)vr < 32u);
  __syncthreads();                              // zero-init visible before staging
  if (rowok)
    *(float4*)&plane[0][sr*38 + 4 + sq] = *(const float4*)(src + vr*160 + sq);
  __syncthreads();
  const int lr2 = tid >> 5, c = tid & 31;      // pixel rows 2*lr2, 2*lr2+1
  for (int ci=0; ci<64; ci++){
    // issue next-ci loads early (latency hides under FMA block)
    float4 nx;
    const bool ld = rowok && (ci < 63);
    if (ld) nx = *(const float4*)(src + (size_t)(ci+1)*25600 + vr*160 + sq);
    const float* P2 = plane[ci & 1];
    float g[4][3];
    {
      const float* pp = &P2[(2*lr2)*38 + c + 3];
      g[0][0]=pp[0];   g[0][1]=pp[1];   g[0][2]=pp[2];
      g[1][0]=pp[38];  g[1][1]=pp[39];  g[1][2]=pp[40];
      g[2][0]=pp[76];  g[2][1]=pp[77];  g[2][2]=pp[78];
      g[3][0]=pp[114]; g[3][1]=pp[115]; g[3][2]=pp[116];
    }
    const float* wrow = w + ci*576 + cog*72;   // 72 contiguous dwords -> s_load_dwordx16
    #pragma unroll
    for (int co=0;co<8;co++){
      const float* wp = wrow + co*9;
      float w0=wp[0],w1=wp[1],w2=wp[2],w3=wp[3],w4=wp[4],w5=wp[5],w6=wp[6],w7=wp[7],w8=wp[8];
      acc[0][co] += g[0][0]*w0+g[0][1]*w1+g[0][2]*w2+g[1][0]*w3+g[1][1]*w4
                  + g[1][2]*w5+g[2][0]*w6+g[2][1]*w7+g[2][2]*w8;
      acc[1][co] += g[1][0]*w0+g[1][1]*w1+g[1][2]*w2+g[2][0]*w3+g[2][1]*w4
                  + g[2][2]*w5+g[3][0]*w6+g[3][1]*w7+g[3][2]*w8;
    }
    if (ld) *(float4*)&plane[(ci+1)&1][sr*38 + 4 + sq] = nx;
    __syncthreads();
  }
  #pragma unroll
  for (int k=0;k<2;k++){
    int si = th0 + 2*lr2 + k;
    int h = si*5 + bi, wq = c*5 + bj;
    #pragma unroll
    for (int co=0;co<8;co++){
      int ch = b*64 + cog*8 + co;
      out[(size_t)ch*25600 + h*160 + wq] = lrelu(acc[k][co]);
    }
  }
}

// ---------------- ang: per-macropixel (5x5) 3x3 conv, row-per-thread ------
// Weights pre-repacked: per ci, 36 contiguous dwords at ci*576 + cog*36.
// grid: 1024 1-D swizzled (64 tiles x 16 cogroups of 4co).
__global__ __launch_bounds__(320) void k_ang(const float* __restrict__ bufA, const float* __restrict__ w,
                                             float* __restrict__ out){
  const int P = blockIdx.x;
  const int within = P >> 3, cog = within & 15, tsel = within >> 4;
  const int tg = (P & 7)*8 + tsel;             // 0..63
  const int b = tg >> 4, mip = tg & 15;
  const int tid = threadIdx.x;
  // per-buffer floats: [mi][7][164] = 2296
  __shared__ float lds[2][2296];
  for (int i=tid; i<2*2296; i+=320) ((float*)lds)[i] = 0.f;

  const int u = tid >> 6, mi_l = (tid >> 5) & 1, mp = tid & 31;
  int ro[3];
  #pragma unroll
  for (int du=0; du<3; du++)
    ro[du] = mi_l*1148 + (u+du)*164 + mp*5;    // tap row = 1+(u-1)+du = u+du
  // staging: 400 float4 slots (10 rows x 40); s0 = tid (rows 0..7), s1 = tid+320 (tid<80, rows 8,9)
  const bool st1 = tid < 80;
  const int rr0 = tid/40,       q0 = tid%40;
  const int rr1 = (tid+320)/40, q1 = (tid+320)%40;
  const int dst0 = (rr0/5)*1148 + (1 + rr0%5)*164 + q0*4;
  const int dst1 = (rr1/5)*1148 + (1 + rr1%5)*164 + q1*4;
  const float* src = bufA + (size_t)b*1638400 + (size_t)(mip*10)*160;

  float acc[4][5];
  #pragma unroll
  for (int co=0;co<4;co++)
    #pragma unroll
    for (int v=0;v<5;v++) acc[co][v]=0.f;

  __syncthreads();                       // zero-init visible
  {
    *(float4*)&lds[0][dst0] = *(const float4*)(src + rr0*160 + q0*4);
    if (st1)
      *(float4*)&lds[0][dst1] = *(const float4*)(src + rr1*160 + q1*4);
  }
  __syncthreads();
  for (int ci=0; ci<64; ci++){
    float4 n0, n1;
    if (ci < 63){
      n0 = *(const float4*)(src + (size_t)(ci+1)*25600 + rr0*160 + q0*4);
      if (st1) n1 = *(const float4*)(src + (size_t)(ci+1)*25600 + rr1*160 + q1*4);
    }
    const float* Pb = lds[ci & 1];
    float c[3][5];
    #pragma unroll
    for (int du=0;du<3;du++){
      const float* rp = &Pb[ro[du]];
      c[du][0]=rp[0]; c[du][1]=rp[1]; c[du][2]=rp[2]; c[du][3]=rp[3]; c[du][4]=rp[4];
    }
    const float* wrow = w + ci*576 + cog*36;   // 36 contiguous dwords
    #pragma unroll
    for (int co=0;co<4;co++){
      const float* wp = wrow + co*9;
      float w0=wp[0],w1=wp[1],w2=wp[2],w3=wp[3],w4=wp[4],w5=wp[5],w6=wp[6],w7=wp[7],w8=wp[8];
      acc[co][0] += c[0][0]*w1 + c[0][1]*w2
                  + c[1][0]*w4 + c[1][1]*w5
                  + c[2][0]*w7 + c[2][1]*w8;
      acc[co][1] += c[0][0]*w0 + c[0][1]*w1 + c[0][2]*w2
                  + c[1][0]*w3 + c[1][1]*w4 + c[1][2]*w5
                  + c[2][0]*w6 + c[2][1]*w7 + c[2][2]*w8;
      acc[co][2] += c[0][1]*w0 + c[0][2]*w1 + c[0][3]*w2
                  + c[1][1]*w3 + c[1][2]*w4 + c[1][3]*w5
                  + c[2][1]*w6 + c[2][2]*w7 + c[2][3]*w8;
      acc[co][3] += c[0][2]*w0 + c[0][3]*w1 + c[0][4]*w2
                  + c[1][2]*w3 + c[1][3]*w4 + c[1][4]*w5
                  + c[2][2]*w6 + c[2][3]*w7 + c[2][4]*w8;
      acc[co][4] += c[0][3]*w0 + c[0][4]*w1
                  + c[1][3]*w3 + c[1][4]*w4
                  + c[2][3]*w6 + c[2][4]*w7;
    }
    if (ci < 63){
      float* Q = lds[(ci+1)&1];
      *(float4*)&Q[dst0] = n0;
      if (st1) *(float4*)&Q[dst1] = n1;
    }
    __syncthreads();
  }
  const int h = (mip*2 + mi_l)*5 + u;
  const int wc0 = mp*5;
  #pragma unroll
  for (int co=0;co<4;co++){
    int ch = b*64 + cog*4 + co;
    float* op = out + (size_t)ch*25600 + (size_t)h*160 + wc0;
    op[0]=lrelu(acc[co][0]); op[1]=lrelu(acc[co][1]); op[2]=lrelu(acc[co][2]);
    op[3]=lrelu(acc[co][3]); op[4]=lrelu(acc[co][4]);
  }
}

// ---------------- fused EPI: [1,15]s5p5 + lrelu + 1x1 64->320 + shuffle ---
// Window-split: block = (b, hw, half); handles 16 of 32 windows. Local tap idx
// 3 + wvl*5 + t in [3,93); stage x in [80h-8, 80h+88) -> rowp[64][96] (28KB total).
// y2s stride 84. grid 1280 (= B*160*2), 320 threads.
__global__ __launch_bounds__(320) void k_epi(const float* __restrict__ bufA, const float* __restrict__ we1,
                                             const float* __restrict__ we2, float* __restrict__ out){
  const int bb = blockIdx.x >> 1, half = blockIdx.x & 1;
  const int b = bb / 160, hw = bb % 160;
  const int tid = threadIdx.x;
  __shared__ float rowp[64*96];    // per-ci 96 cols; reused as y2s (64 x 84)
  __shared__ float y1s[64*16];
  // stage: 22 float4 per ci (88 valid floats) + 8 zero cols
  const int lofs = half ? 0 : 8;   // local col of first staged float
  const int xofs = half ? 72 : 0;  // global x of first staged float
  for (int ft=tid; ft<1408; ft+=320){
    int ci = ft/22, q = ft - ci*22;
    *(float4*)&rowp[ci*96 + lofs + q*4] =
      *(const float4*)(bufA + (size_t)b*1638400 + (size_t)ci*25600 + (size_t)hw*160 + xofs + q*4);
  }
  for (int idx=tid; idx<512; idx+=320){
    int ci = idx>>3, j = idx&7;
    rowp[ci*96 + (half ? 88+j : j)] = 0.f;
  }
  __syncthreads();
  // conv1: 4 windows per thread (256 active). taps at local idx 3 + wvl*5 + t.
  if (tid < 256){
    const int co = tid >> 2, wvl0 = (tid & 3)*4;
    const int a0 = 2 + wvl0*5;                // even -> float2-aligned
    float acc[4];
    #pragma unroll
    for (int j=0;j<4;j++) acc[j]=0.f;
    const float* wp0 = we1 + (size_t)co*960;
    for (int ci=0; ci<64; ci++){
      float fl[32];
      const float* rp = &rowp[ci*96 + a0];
      #pragma unroll
      for (int m=0;m<16;m++) *(float2*)&fl[2*m] = *(const float2*)&rp[2*m];
      const float* wp = wp0 + ci*15;
      #pragma unroll
      for (int t=0;t<15;t++){
        float wt = wp[t];
        #pragma unroll
        for (int j=0;j<4;j++) acc[j] += fl[1 + j*5 + t]*wt;
      }
    }
    #pragma unroll
    for (int j=0;j<4;j++) y1s[co*16 + wvl0 + j] = lrelu(acc[j]);
  }
  __syncthreads();
  // conv2 1x1 64->320 over 16 windows; shuffle into y2s[c*84 + wvl*5 + kk]
  {
    const int oc = tid, kk = oc >> 6, c = oc & 63;
    float a2[16];
    #pragma unroll
    for (int wv=0;wv<16;wv++) a2[wv]=0.f;
    const float* wp = we2 + (size_t)oc*64;
    for (int ci=0; ci<64; ci++){
      float wt = wp[ci];
      const float* yp = &y1s[ci*16];
      #pragma unroll
      for (int wv=0; wv<16; wv++) a2[wv] += yp[wv]*wt;
    }
    float* y2s = rowp;
    #pragma unroll
    for (int wv=0; wv<16; wv++) y2s[c*84 + wv*5 + kk] = lrelu(a2[wv]);
  }
  __syncthreads();
  // coalesced writeout: 80 floats per channel at w-range [half*80, half*80+80)
  {
    const float* y2s = rowp;
    for (int k=0;k<4;k++){
      int f = (tid + k*320)*4;               // < 5120
      int c = f/80, rr = f - c*80;
      *(float4*)(out + (size_t)(b*64+c)*25600 + (size_t)hw*160 + half*80 + rr)
        = *(const float4*)&y2s[c*84+rr];
    }
  }
}

// ---------------- permV: per-(b,c) 160x160 transpose src[i][j] -> dst[j][i]
__global__ __launch_bounds__(256) void k_permV(const float* __restrict__ tmp, float* __restrict__ dst){
  const int bc = blockIdx.x;
  const int ti = blockIdx.y / 5, tj = blockIdx.y % 5;
  const int hw0 = ti*32, r0 = tj*32;
  const int lx = threadIdx.x & 31, ly = threadIdx.x >> 5;   // 32 x 8
  __shared__ float tile[32][33];
  const float* in = tmp + (size_t)bc*25600;
  float* outp = dst + (size_t)bc*25600;
  for (int yy=ly; yy<32; yy+=8)
    tile[yy][lx] = in[(size_t)(hw0+yy)*160 + r0 + lx];
  __syncthreads();
  for (int yy=ly; yy<32; yy+=8)
    outp[(size_t)(r0+yy)*160 + hw0 + lx] = tile[lx][yy];
}

// ---------------- permM: mac2sai  newB1[f] = A[ai*32+hh][aj*32+ww], f=hh*800+ww*25+ai*5+aj
__global__ __launch_bounds__(256) void k_permM(const float* __restrict__ A, float* __restrict__ dst){
  const int bc = blockIdx.x >> 5, hh = blockIdx.x & 31;
  const int tid = threadIdx.x;
  __shared__ float rows[5*160];
  const float* in = A + (size_t)bc*25600;
  if (tid < 200){
    int ai = tid/40, q = (tid - ai*40)*4;
    *(float4*)&rows[ai*160 + q] = *(const float4*)(in + (size_t)(ai*32+hh)*160 + q);
  }
  __syncthreads();
  float* outp = dst + (size_t)bc*25600 + (size_t)hh*800;
  for (int t=tid; t<800; t+=256){
    int ww = t/25, r2 = t - ww*25, ai = r2/5, aj = r2 - ai*5;
    outp[t] = rows[ai*160 + aj*32 + ww];
  }
}

// ---------------- single-pass stats: 4 sums + 10 products (E-formula) -----
__global__ __launch_bounds__(256) void k_red(const float* __restrict__ b0, const float* __restrict__ b1,
                                             const float* __restrict__ b2, const float* __restrict__ b3,
                                             float* __restrict__ part){
  const int b = blockIdx.y, blk = blockIdx.x;
  const int tid = threadIdx.x;
  const size_t off = (size_t)b*1638400 + (size_t)blk*25600;
  float s0=0,s1=0,s2=0,s3=0;
  float p00=0,p01=0,p02=0,p03=0,p11=0,p12=0,p13=0,p22=0,p23=0,p33=0;
  for (int it=0; it<25; it++){
    size_t m = off + it*1024 + tid*4;
    float4 x0 = *(const float4*)(b0+m);
    float4 x1 = *(const float4*)(b1+m);
    float4 x2 = *(const float4*)(b2+m);
    float4 x3 = *(const float4*)(b3+m);
    s0 += (x0.x+x0.y)+(x0.z+x0.w);
    s1 += (x1.x+x1.y)+(x1.z+x1.w);
    s2 += (x2.x+x2.y)+(x2.z+x2.w);
    s3 += (x3.x+x3.y)+(x3.z+x3.w);
    p00 += x0.x*x0.x+x0.y*x0.y+x0.z*x0.z+x0.w*x0.w;
    p01 += x0.x*x1.x+x0.y*x1.y+x0.z*x1.z+x0.w*x1.w;
    p02 += x0.x*x2.x+x0.y*x2.y+x0.z*x2.z+x0.w*x2.w;
    p03 += x0.x*x3.x+x0.y*x3.y+x0.z*x3.z+x0.w*x3.w;
    p11 += x1.x*x1.x+x1.y*x1.y+x1.z*x1.z+x1.w*x1.w;
    p12 += x1.x*x2.x+x1.y*x2.y+x1.z*x2.z+x1.w*x2.w;
    p13 += x1.x*x3.x+x1.y*x3.y+x1.z*x3.z+x1.w*x3.w;
    p22 += x2.x*x2.x+x2.y*x2.y+x2.z*x2.z+x2.w*x2.w;
    p23 += x2.x*x3.x+x2.y*x3.y+x2.z*x3.z+x2.w*x3.w;
    p33 += x3.x*x3.x+x3.y*x3.y+x3.z*x3.z+x3.w*x3.w;
  }
  float vals[14] = {s0,s1,s2,s3,p00,p01,p02,p03,p11,p12,p13,p22,p23,p33};
  __shared__ float red[4][14];
  int lane = tid & 63, wv = tid >> 6;
  #pragma unroll
  for (int j=0;j<14;j++){
    float v = vals[j];
    #pragma unroll
    for (int o=32;o>0;o>>=1) v += __shfl_down(v,o,64);
    if (lane==0) red[wv][j]=v;
  }
  __syncthreads();
  if (tid<14) part[((size_t)b*64+blk)*16 + tid] = red[0][tid]+red[1][tid]+red[2][tid]+red[3][tid];
}

// ---- att (4x4) via E-formula, fold attention + identity into fuse1 weights
__global__ __launch_bounds__(256) void k_attW(const float* __restrict__ part,
        const float* __restrict__ alpha, const float* __restrict__ gamma, const float* __restrict__ beta,
        int iblk, const float* __restrict__ wf1, float* __restrict__ Weff){
  const int b = blockIdx.x, tid = threadIdx.x;
  __shared__ float st[14];
  __shared__ float att[16];
  if (tid<14){
    float t=0;
    for (int blk=0;blk<64;blk++) t += part[((size_t)b*64+blk)*16 + tid];
    st[tid]=t;
  }
  __syncthreads();
  if (tid==0){
    const float M = 1638400.f;
    float s[4] = {st[0],st[1],st[2],st[3]};
    float S[4][4];
    S[0][0]=st[4];  S[0][1]=S[1][0]=st[5];  S[0][2]=S[2][0]=st[6];  S[0][3]=S[3][0]=st[7];
    S[1][1]=st[8];  S[1][2]=S[2][1]=st[9];  S[1][3]=S[3][1]=st[10];
    S[2][2]=st[11]; S[2][3]=S[3][2]=st[12]; S[3][3]=st[13];
    float al=alpha[iblk], ga=gamma[iblk], be=beta[iblk];
    float scale = al/(M-1.f);
    float cov[4][4], ss=0.f;
    for (int n=0;n<4;n++) for (int k=0;k<4;k++){
      float c = (S[n][k] - s[n]*s[k]/M)*scale;
      cov[n][k]=c; ss += c*c;
    }
    float rms = sqrtf(ss/16.f + 1e-5f);
    for (int n=0;n<4;n++) for (int k=0;k<4;k++){
      float g = ga*cov[n][k]/rms + be;
      att[n*4+k] = g/(1.f+expf(-g));
    }
  }
  __syncthreads();
  for (int idx=tid; idx<16384; idx+=256){
    int co=idx>>8, kc=idx&255, k=kc>>6, c=kc&63;
    float v = wf1[co*256+kc];
    #pragma unroll
    for (int n=0;n<4;n++) v += att[n*4+k]*wf1[co*256+n*64+c];
    Weff[(size_t)b*16384+idx] = v;
  }
}

// ---------------- fuse1: per-batch GEMM 64x256 @ 256x25600, float4-blocked
__global__ __launch_bounds__(256) void k_fuse1(const float* b0, const float* __restrict__ b1,
                                               const float* __restrict__ b2, const float* __restrict__ b3,
                                               const float* __restrict__ Weff, float* y64){
  const int tile = blockIdx.x, b = blockIdx.y;
  const int px0 = tile*64;
  const int tid = threadIdx.x;
  const int ti = tid >> 4, tj = tid & 15;      // co = ti*4.., px = tj*4..
  __shared__ float xs[64][68];                 // [k2][px]
  __shared__ float wt[64][68];                 // [k2][co]
  float acc[4][4];
  #pragma unroll
  for (int i=0;i<4;i++)
    #pragma unroll
    for (int j=0;j<4;j++) acc[i][j]=0.f;
  const float* bptr[4] = {b0,b1,b2,b3};
  for (int kb=0; kb<4; kb++){
    const float* xbk = bptr[kb] + (size_t)b*1638400 + px0;
    const float* wb = Weff + (size_t)b*16384 + kb*64;
    __syncthreads();
    for (int idx=tid; idx<4096; idx+=256){
      int kc=idx>>6, px=idx&63;
      xs[kc][px] = xbk[(size_t)kc*25600 + px];
    }
    for (int idx=tid; idx<4096; idx+=256){
      int co=idx>>6, k2=idx&63;
      wt[k2][co] = wb[co*256 + k2];
    }
    __syncthreads();
    for (int k2=0;k2<64;k2++){
      float4 a = *(const float4*)&wt[k2][ti*4];
      float4 v = *(const float4*)&xs[k2][tj*4];
      acc[0][0]+=a.x*v.x; acc[0][1]+=a.x*v.y; acc[0][2]+=a.x*v.z; acc[0][3]+=a.x*v.w;
      acc[1][0]+=a.y*v.x; acc[1][1]+=a.y*v.y; acc[1][2]+=a.y*v.z; acc[1][3]+=a.y*v.w;
      acc[2][0]+=a.z*v.x; acc[2][1]+=a.z*v.y; acc[2][2]+=a.z*v.z; acc[2][3]+=a.z*v.w;
      acc[3][0]+=a.w*v.x; acc[3][1]+=a.w*v.y; acc[3][2]+=a.w*v.z; acc[3][3]+=a.w*v.w;
    }
  }
  #pragma unroll
  for (int i=0;i<4;i++){
    int co = ti*4 + i;
    float4 o = make_float4(lrelu(acc[i][0]), lrelu(acc[i][1]), lrelu(acc[i][2]), lrelu(acc[i][3]));
    *(float4*)(y64 + ((size_t)(b*64+co))*25600 + px0 + tj*4) = o;
  }
}

// ---------------- fuse2: dilated 3x3 (dil 5, pad 5) + residual ------------
// 16x32 tiles, double-buffered LDS plane 26x48 (aligned float4 halo, cols tw0-8..tw0+39),
// group-predicated float4 staging, one barrier per ci (BK=1), 8 co per block.
// Weights pre-repacked: per ci, 72 contiguous dwords at ci*576 + cog*72.
// grid: 1600 1-D swizzled (200 tiles x 8 cogroups of 8co).
template<int FINAL>
__global__ __launch_bounds__(256) void k_fuse2(const float* __restrict__ y64, const float* resid,
                                               const float* __restrict__ w, float* outp){
  const int P = blockIdx.x;
  const int within = P >> 3, cog = within & 7, tsel = within >> 3;
  const int tg = (P & 7)*25 + tsel;            // 0..199
  const int b = tg / 50, tile = tg % 50;
  const int th0 = (tile/5)*16, tw0 = (tile%5)*32;
  const int tid = threadIdx.x;
  __shared__ float plane[2][26*48];   // plane row r = global row th0-5+r; col cc = global col tw0-8+cc
  float acc[2][8];
  #pragma unroll
  for (int k=0;k<2;k++)
    #pragma unroll
    for (int c=0;c<8;c++) acc[k][c]=0.f;
  const float* src = y64 + (size_t)b*1638400;
  // staging: 26 rows x 12 float4 = 312 slots; slot tid always, slot tid+256 iff tid<56
  const int s0r = tid/12,        s0c = tid - (tid/12)*12;
  const int s1i = tid + 256;
  const int s1r = s1i/12,        s1c = s1i - (s1i/12)*12;
  const bool has1 = tid < 56;
  const int g0h = th0 - 5 + s0r, g0w = tw0 - 8 + s0c*4;
  const int g1h = th0 - 5 + s1r, g1w = tw0 - 8 + s1c*4;
  const bool v0 = ((unsigned)g0h < 160u) && ((unsigned)g0w < 160u);
  const bool v1 = has1 && ((unsigned)g1h < 160u) && ((unsigned)g1w < 160u);
  const int go0 = g0h*160 + g0w, go1 = g1h*160 + g1w;
  const int d0 = s0r*48 + s0c*4, d1 = s1r*48 + s1c*4;
  const float4 z4 = make_float4(0.f,0.f,0.f,0.f);
  // prologue: stage ci=0 (OOB groups -> zero = implicit pad)
  {
    float4 x0 = v0 ? *(const float4*)(src + go0) : z4;
    *(float4*)&plane[0][d0] = x0;
    if (has1){
      float4 x1 = v1 ? *(const float4*)(src + go1) : z4;
      *(float4*)&plane[0][d1] = x1;
    }
  }
  __syncthreads();
  const int lr = tid >> 5, c = tid & 31;
  const int tap = lr*48 + c + 3;
  for (int ci=0; ci<64; ci++){
    // issue next-ci loads early
    float4 n0, n1;
    if (ci < 63){
      const float* sN = src + (size_t)(ci+1)*25600;
      n0 = v0 ? *(const float4*)(sN + go0) : z4;
      if (has1) n1 = v1 ? *(const float4*)(sN + go1) : z4;
    }
    const float* Pb = plane[ci & 1];
    float t0[9], t1[9];
    {
      const float* pp = &Pb[tap];
      t0[0]=pp[0];      t0[1]=pp[5];      t0[2]=pp[10];
      t0[3]=pp[240];    t0[4]=pp[245];    t0[5]=pp[250];
      t0[6]=pp[480];    t0[7]=pp[485];    t0[8]=pp[490];
      const float* qq = pp + 8*48;
      t1[0]=qq[0];      t1[1]=qq[5];      t1[2]=qq[10];
      t1[3]=qq[240];    t1[4]=qq[245];    t1[5]=qq[250];
      t1[6]=qq[480];    t1[7]=qq[485];    t1[8]=qq[490];
    }
    const float* wrow = w + ci*576 + cog*72;   // 72 contiguous dwords -> s_load_dwordx16
    #pragma unroll
    for (int co=0;co<8;co++){
      const float* wp = wrow + co*9;
      float w0=wp[0],w1=wp[1],w2=wp[2],w3=wp[3],w4=wp[4],w5=wp[5],w6=wp[6],w7=wp[7],w8=wp[8];
      acc[0][co] += t0[0]*w0+t0[1]*w1+t0[2]*w2+t0[3]*w3+t0[4]*w4
                  + t0[5]*w5+t0[6]*w6+t0[7]*w7+t0[8]*w8;
      acc[1][co] += t1[0]*w0+t1[1]*w1+t1[2]*w2+t1[3]*w3+t1[4]*w4
                  + t1[5]*w5+t1[6]*w6+t1[7]*w7+t1[8]*w8;
    }
    if (ci < 63){
      float* Q = plane[(ci+1)&1];
      *(float4*)&Q[d0] = n0;
      if (has1) *(float4*)&Q[d1] = n1;
    }
    __syncthreads();
  }
  #pragma unroll
  for (int k=0;k<2;k++){
    int h = th0 + lr + k*8, wq = tw0 + c;
    #pragma unroll
    for (int co=0;co<8;co++){
      int cg = cog*8 + co;
      size_t base = ((size_t)(b*64+cg)*160 + h)*160 + wq;
      outp[base] = acc[k][co] + resid[base];
    }
  }
}

extern "C" void kernel_launch(void* const* d_in, const int* in_sizes, int n_in,
                              void* d_out, int out_size, void* d_ws, size_t ws_size,
                              hipStream_t stream){
  const float* x    = (const float*)d_in[0];
  const float* x1   = (const float*)d_in[1];
  const float* wspa = (const float*)d_in[2];
  const float* wang = (const float*)d_in[3];
  const float* we1  = (const float*)d_in[4];
  const float* we2  = (const float*)d_in[5];
  const float* al   = (const float*)d_in[6];
  const float* ga   = (const float*)d_in[7];
  const float* be   = (const float*)d_in[8];
  const float* wf1  = (const float*)d_in[9];
  const float* wf2  = (const float*)d_in[10];

  char* ws = (char*)d_ws;
  const size_t SLOT = 26214400;
  float* A  = (float*)(ws);          // MacPI buf (in-place residual chain)
  float* Bv = (float*)(ws +   SLOT); // B1 input / branchV / newB1
  float* T1 = (float*)(ws + 2*SLOT); // branchSpa -> y64 in-place
  float* T2 = (float*)(ws + 3*SLOT); // epiV tmp -> branchAng
  float* part = (float*)(ws + 4*SLOT);            // 4*64*16 f32 (16KB)
  float* Weff = (float*)(ws + 4*SLOT + 16384);    // 4*64*256 f32 (256KB)
  float* Wrep = (float*)(ws + 4*SLOT + 16384 + 262144);  // 3*4*36864 f32 (1.7MB)
  float* WspaR = Wrep;
  float* WangR = Wrep + 147456;
  float* Wf2R  = Wrep + 2*147456;
  float* D = (float*)d_out;          // A^T / branchH scratch; final output at the end

  k_wrep<<<1728,256,0,stream>>>(wspa, wang, wf2, Wrep);

  for (int i=0;i<4;i++){
    const float* Asrc  = (i==0) ? x  : (const float*)A;
    const float* B1src = (i==0) ? x1 : (const float*)Bv;
    k_permV<<<dim3(256,25),256,0,stream>>>(Asrc, D);                             // D = Asrc^T
    k_epi<<<1280,320,0,stream>>>(D, we1 + (size_t)i*61440, we2 + (size_t)i*20480, T2);   // epiV (tmp layout)
    k_spa<<<1600,256,0,stream>>>(B1src, WspaR + (size_t)i*36864, T1);
    k_permV<<<dim3(256,25),256,0,stream>>>(T2, Bv);                              // branchV
    k_ang<<<1024,320,0,stream>>>(Asrc, WangR + (size_t)i*36864, T2);
    k_epi<<<1280,320,0,stream>>>(Asrc, we1 + (size_t)i*61440, we2 + (size_t)i*20480, D); // branchH
    k_red<<<dim3(64,4),256,0,stream>>>(T1, T2, D, Bv, part);
    k_attW<<<4,256,0,stream>>>(part, al, ga, be, i, wf1 + (size_t)i*16384, Weff);
    k_fuse1<<<dim3(400,4),256,0,stream>>>(T1, T2, D, Bv, Weff, T1);
    if (i<3){
      k_fuse2<0><<<1600,256,0,stream>>>(T1, Asrc, Wf2R + (size_t)i*36864, A);
      k_permM<<<8192,256,0,stream>>>(A, Bv);
    } else {
      k_fuse2<1><<<1600,256,0,stream>>>(T1, Asrc, Wf2R + (size_t)i*36864, D);
    }
  }
}

// Round 14
// 2740.784 us; speedup vs baseline: 1.0706x; 1.0241x over previous
//
#include <hip/hip_runtime.h>

__device__ __forceinline__ float lrelu(float v){ return v >= 0.f ? v : 0.1f*v; }

// Dims: B=4, C=64, H=W=160, HW=25600, per-tensor (B,64,160,160) f32: batch stride 1,638,400
// ws: 4 f32 slots x 26,214,400 B (A, Bv, T1, T2) + part/Weff/Wrep tail. branchH in d_out.
// XCD swizzle: P = ((tsel*NC + cog) << 3) | xcd -> cogroups of a tile temporally adjacent.
// Lessons: BK=2 regresses always; co=16 regresses (weight stream); occupancy needs grid>=1280;
// conflicts fixed (float4 halo / stride-164 / stride-40); weight repack ~neutral.
// R14: WAVE-SYNCHRONOUS spa/fuse2 — per-wave private LDS staging of exactly the rows that
// wave reads; same-wave ds_write->ds_read ordered by lgkmcnt; ZERO s_barrier in kernel.

// ---------------- weight repack: [4][64co][64ci][9] -> [4][64ci][64co][9], 3 tensors
__global__ __launch_bounds__(256) void k_wrep(const float* __restrict__ wspa, const float* __restrict__ wang,
                                              const float* __restrict__ wf2, float* __restrict__ outp){
  int id = blockIdx.x*256 + threadIdx.x;       // < 442368
  int t = id / 147456, r = id - t*147456;
  int i = r / 36864,  e = r - i*36864;
  int ci = e / 576,   r3 = e - ci*576;
  int co = r3 / 9,    j = r3 - co*9;
  const float* src = (t==0 ? wspa : (t==1 ? wang : wf2));
  outp[id] = src[(size_t)i*36864 + co*576 + ci*9 + j];
}

// ---------------- spa: per-view 3x3 conv (zero pad at view edges) ----------
// Wave-synchronous: wave wv owns pixel rows 4wv..4wv+3; stages its 6 tap rows
// (view rows th0+4wv-1 .. th0+4wv+4) into private wl[wv]; no barriers.
// grid: 1600 1-D swizzled (200 tiles x 8 cogroups of 8co).
__global__ __launch_bounds__(256) void k_spa(const float* __restrict__ buf1, const float* __restrict__ w,
                                             float* __restrict__ out){
  const int P = blockIdx.x;
  const int within = P >> 3, cog = within & 7, tsel = within >> 3;
  const int tg = (P & 7)*25 + tsel;            // 0..199
  const int b = tg / 50, r2 = tg % 50;
  const int view = r2 >> 1, half = r2 & 1;
  const int bi = view / 5, bj = view % 5;
  const int th0 = half*16;
  const int tid = threadIdx.x;
  const int wv = tid >> 6, lane = tid & 63;
  __shared__ float wl[4][2][240];   // per-wave: 6 rows x 40 (data cols 4..35, zeros 3/36), 2 bufs
  for (int i=lane; i<480; i+=64) ((float*)wl[wv])[i] = 0.f;
  float acc[2][8];
  #pragma unroll
  for (int k=0;k<2;k++)
    #pragma unroll
    for (int c2=0;c2<8;c2++) acc[k][c2]=0.f;
  const float* src = buf1 + (size_t)b*1638400 + bi*32*160 + bj*32;
  // staging: 48 slots (6 rows x 8 float4); lane<48 handles one
  const int srow = lane >> 3, sq = (lane & 7)*4;
  const int vr = th0 + 4*wv - 1 + srow;
  const bool rowok = (lane < 48) && ((unsigned)vr < 32u);
  const int dst = srow*40 + 4 + sq;
  if (rowok)
    *(float4*)&wl[wv][0][dst] = *(const float4*)(src + vr*160 + sq);
  const int lrl = (tid >> 5) & 1, c = tid & 31;
  for (int ci=0; ci<64; ci++){
    float4 nx;
    const bool ld = rowok && (ci < 63);
    if (ld) nx = *(const float4*)(src + (size_t)(ci+1)*25600 + vr*160 + sq);
    const float* Pb = wl[wv][ci & 1];
    float g[4][3];
    {
      const float* pp = &Pb[(2*lrl)*40 + c + 3];
      g[0][0]=pp[0];   g[0][1]=pp[1];   g[0][2]=pp[2];
      g[1][0]=pp[40];  g[1][1]=pp[41];  g[1][2]=pp[42];
      g[2][0]=pp[80];  g[2][1]=pp[81];  g[2][2]=pp[82];
      g[3][0]=pp[120]; g[3][1]=pp[121]; g[3][2]=pp[122];
    }
    const float* wrow = w + ci*576 + cog*72;   // repacked: 72 contiguous dwords
    #pragma unroll
    for (int co=0;co<8;co++){
      const float* wp = wrow + co*9;
      float w0=wp[0],w1=wp[1],w2=wp[2],w3=wp[3],w4=wp[4],w5=wp[5],w6=wp[6],w7=wp[7],w8=wp[8];
      acc[0][co] += g[0][0]*w0+g[0][1]*w1+g[0][2]*w2+g[1][0]*w3+g[1][1]*w4
                  + g[1][2]*w5+g[2][0]*w6+g[2][1]*w7+g[2][2]*w8;
      acc[1][co] += g[1][0]*w0+g[1][1]*w1+g[1][2]*w2+g[2][0]*w3+g[2][1]*w4
                  + g[2][2]*w5+g[3][0]*w6+g[3][1]*w7+g[3][2]*w8;
    }
    if (ld) *(float4*)&wl[wv][(ci+1)&1][dst] = nx;
  }
  #pragma unroll
  for (int k=0;k<2;k++){
    int si = th0 + 4*wv + 2*lrl + k;
    int h = si*5 + bi, wq = c*5 + bj;
    #pragma unroll
    for (int co=0;co<8;co++){
      int ch = b*64 + cog*8 + co;
      out[(size_t)ch*25600 + h*160 + wq] = lrelu(acc[k][co]);
    }
  }
}

// ---------------- ang: per-macropixel (5x5) 3x3 conv, row-per-thread ------
// (unchanged from R13: barrier version, stride-164, repacked weights)
__global__ __launch_bounds__(320) void k_ang(const float* __restrict__ bufA, const float* __restrict__ w,
                                             float* __restrict__ out){
  const int P = blockIdx.x;
  const int within = P >> 3, cog = within & 15, tsel = within >> 4;
  const int tg = (P & 7)*8 + tsel;             // 0..63
  const int b = tg >> 4, mip = tg & 15;
  const int tid = threadIdx.x;
  __shared__ float lds[2][2296];
  for (int i=tid; i<2*2296; i+=320) ((float*)lds)[i] = 0.f;

  const int u = tid >> 6, mi_l = (tid >> 5) & 1, mp = tid & 31;
  int ro[3];
  #pragma unroll
  for (int du=0; du<3; du++)
    ro[du] = mi_l*1148 + (u+du)*164 + mp*5;
  const bool st1 = tid < 80;
  const int rr0 = tid/40,       q0 = tid%40;
  const int rr1 = (tid+320)/40, q1 = (tid+320)%40;
  const int dst0 = (rr0/5)*1148 + (1 + rr0%5)*164 + q0*4;
  const int dst1 = (rr1/5)*1148 + (1 + rr1%5)*164 + q1*4;
  const float* src = bufA + (size_t)b*1638400 + (size_t)(mip*10)*160;

  float acc[4][5];
  #pragma unroll
  for (int co=0;co<4;co++)
    #pragma unroll
    for (int v=0;v<5;v++) acc[co][v]=0.f;

  __syncthreads();
  {
    *(float4*)&lds[0][dst0] = *(const float4*)(src + rr0*160 + q0*4);
    if (st1)
      *(float4*)&lds[0][dst1] = *(const float4*)(src + rr1*160 + q1*4);
  }
  __syncthreads();
  for (int ci=0; ci<64; ci++){
    float4 n0, n1;
    if (ci < 63){
      n0 = *(const float4*)(src + (size_t)(ci+1)*25600 + rr0*160 + q0*4);
      if (st1) n1 = *(const float4*)(src + (size_t)(ci+1)*25600 + rr1*160 + q1*4);
    }
    const float* Pb = lds[ci & 1];
    float c[3][5];
    #pragma unroll
    for (int du=0;du<3;du++){
      const float* rp = &Pb[ro[du]];
      c[du][0]=rp[0]; c[du][1]=rp[1]; c[du][2]=rp[2]; c[du][3]=rp[3]; c[du][4]=rp[4];
    }
    const float* wrow = w + ci*576 + cog*36;
    #pragma unroll
    for (int co=0;co<4;co++){
      const float* wp = wrow + co*9;
      float w0=wp[0],w1=wp[1],w2=wp[2],w3=wp[3],w4=wp[4],w5=wp[5],w6=wp[6],w7=wp[7],w8=wp[8];
      acc[co][0] += c[0][0]*w1 + c[0][1]*w2
                  + c[1][0]*w4 + c[1][1]*w5
                  + c[2][0]*w7 + c[2][1]*w8;
      acc[co][1] += c[0][0]*w0 + c[0][1]*w1 + c[0][2]*w2
                  + c[1][0]*w3 + c[1][1]*w4 + c[1][2]*w5
                  + c[2][0]*w6 + c[2][1]*w7 + c[2][2]*w8;
      acc[co][2] += c[0][1]*w0 + c[0][2]*w1 + c[0][3]*w2
                  + c[1][1]*w3 + c[1][2]*w4 + c[1][3]*w5
                  + c[2][1]*w6 + c[2][2]*w7 + c[2][3]*w8;
      acc[co][3] += c[0][2]*w0 + c[0][3]*w1 + c[0][4]*w2
                  + c[1][2]*w3 + c[1][3]*w4 + c[1][4]*w5
                  + c[2][2]*w6 + c[2][3]*w7 + c[2][4]*w8;
      acc[co][4] += c[0][3]*w0 + c[0][4]*w1
                  + c[1][3]*w3 + c[1][4]*w4
                  + c[2][3]*w6 + c[2][4]*w7;
    }
    if (ci < 63){
      float* Q = lds[(ci+1)&1];
      *(float4*)&Q[dst0] = n0;
      if (st1) *(float4*)&Q[dst1] = n1;
    }
    __syncthreads();
  }
  const int h = (mip*2 + mi_l)*5 + u;
  const int wc0 = mp*5;
  #pragma unroll
  for (int co=0;co<4;co++){
    int ch = b*64 + cog*4 + co;
    float* op = out + (size_t)ch*25600 + (size_t)h*160 + wc0;
    op[0]=lrelu(acc[co][0]); op[1]=lrelu(acc[co][1]); op[2]=lrelu(acc[co][2]);
    op[3]=lrelu(acc[co][3]); op[4]=lrelu(acc[co][4]);
  }
}

// ---------------- fused EPI (unchanged from R13) --------------------------
__global__ __launch_bounds__(320) void k_epi(const float* __restrict__ bufA, const float* __restrict__ we1,
                                             const float* __restrict__ we2, float* __restrict__ out){
  const int bb = blockIdx.x >> 1, half = blockIdx.x & 1;
  const int b = bb / 160, hw = bb % 160;
  const int tid = threadIdx.x;
  __shared__ float rowp[64*96];
  __shared__ float y1s[64*16];
  const int lofs = half ? 0 : 8;
  const int xofs = half ? 72 : 0;
  for (int ft=tid; ft<1408; ft+=320){
    int ci = ft/22, q = ft - ci*22;
    *(float4*)&rowp[ci*96 + lofs + q*4] =
      *(const float4*)(bufA + (size_t)b*1638400 + (size_t)ci*25600 + (size_t)hw*160 + xofs + q*4);
  }
  for (int idx=tid; idx<512; idx+=320){
    int ci = idx>>3, j = idx&7;
    rowp[ci*96 + (half ? 88+j : j)] = 0.f;
  }
  __syncthreads();
  if (tid < 256){
    const int co = tid >> 2, wvl0 = (tid & 3)*4;
    const int a0 = 2 + wvl0*5;
    float acc[4];
    #pragma unroll
    for (int j=0;j<4;j++) acc[j]=0.f;
    const float* wp0 = we1 + (size_t)co*960;
    for (int ci=0; ci<64; ci++){
      float fl[32];
      const float* rp = &rowp[ci*96 + a0];
      #pragma unroll
      for (int m=0;m<16;m++) *(float2*)&fl[2*m] = *(const float2*)&rp[2*m];
      const float* wp = wp0 + ci*15;
      #pragma unroll
      for (int t=0;t<15;t++){
        float wt = wp[t];
        #pragma unroll
        for (int j=0;j<4;j++) acc[j] += fl[1 + j*5 + t]*wt;
      }
    }
    #pragma unroll
    for (int j=0;j<4;j++) y1s[co*16 + wvl0 + j] = lrelu(acc[j]);
  }
  __syncthreads();
  {
    const int oc = tid, kk = oc >> 6, c = oc & 63;
    float a2[16];
    #pragma unroll
    for (int wv2=0;wv2<16;wv2++) a2[wv2]=0.f;
    const float* wp = we2 + (size_t)oc*64;
    for (int ci=0; ci<64; ci++){
      float wt = wp[ci];
      const float* yp = &y1s[ci*16];
      #pragma unroll
      for (int wv2=0; wv2<16; wv2++) a2[wv2] += yp[wv2]*wt;
    }
    float* y2s = rowp;
    #pragma unroll
    for (int wv2=0; wv2<16; wv2++) y2s[c*84 + wv2*5 + kk] = lrelu(a2[wv2]);
  }
  __syncthreads();
  {
    const float* y2s = rowp;
    for (int k=0;k<4;k++){
      int f = (tid + k*320)*4;
      int c = f/80, rr = f - c*80;
      *(float4*)(out + (size_t)(b*64+c)*25600 + (size_t)hw*160 + half*80 + rr)
        = *(const float4*)&y2s[c*84+rr];
    }
  }
}

// ---------------- permV (unchanged) ----------------------------------------
__global__ __launch_bounds__(256) void k_permV(const float* __restrict__ tmp, float* __restrict__ dst){
  const int bc = blockIdx.x;
  const int ti = blockIdx.y / 5, tj = blockIdx.y % 5;
  const int hw0 = ti*32, r0 = tj*32;
  const int lx = threadIdx.x & 31, ly = threadIdx.x >> 5;
  __shared__ float tile[32][33];
  const float* in = tmp + (size_t)bc*25600;
  float* outp = dst + (size_t)bc*25600;
  for (int yy=ly; yy<32; yy+=8)
    tile[yy][lx] = in[(size_t)(hw0+yy)*160 + r0 + lx];
  __syncthreads();
  for (int yy=ly; yy<32; yy+=8)
    outp[(size_t)(r0+yy)*160 + hw0 + lx] = tile[lx][yy];
}

// ---------------- permM (unchanged) ----------------------------------------
__global__ __launch_bounds__(256) void k_permM(const float* __restrict__ A, float* __restrict__ dst){
  const int bc = blockIdx.x >> 5, hh = blockIdx.x & 31;
  const int tid = threadIdx.x;
  __shared__ float rows[5*160];
  const float* in = A + (size_t)bc*25600;
  if (tid < 200){
    int ai = tid/40, q = (tid - ai*40)*4;
    *(float4*)&rows[ai*160 + q] = *(const float4*)(in + (size_t)(ai*32+hh)*160 + q);
  }
  __syncthreads();
  float* outp = dst + (size_t)bc*25600 + (size_t)hh*800;
  for (int t=tid; t<800; t+=256){
    int ww = t/25, r2 = t - ww*25, ai = r2/5, aj = r2 - ai*5;
    outp[t] = rows[ai*160 + aj*32 + ww];
  }
}

// ---------------- k_red (unchanged) ----------------------------------------
__global__ __launch_bounds__(256) void k_red(const float* __restrict__ b0, const float* __restrict__ b1,
                                             const float* __restrict__ b2, const float* __restrict__ b3,
                                             float* __restrict__ part){
  const int b = blockIdx.y, blk = blockIdx.x;
  const int tid = threadIdx.x;
  const size_t off = (size_t)b*1638400 + (size_t)blk*25600;
  float s0=0,s1=0,s2=0,s3=0;
  float p00=0,p01=0,p02=0,p03=0,p11=0,p12=0,p13=0,p22=0,p23=0,p33=0;
  for (int it=0; it<25; it++){
    size_t m = off + it*1024 + tid*4;
    float4 x0 = *(const float4*)(b0+m);
    float4 x1 = *(const float4*)(b1+m);
    float4 x2 = *(const float4*)(b2+m);
    float4 x3 = *(const float4*)(b3+m);
    s0 += (x0.x+x0.y)+(x0.z+x0.w);
    s1 += (x1.x+x1.y)+(x1.z+x1.w);
    s2 += (x2.x+x2.y)+(x2.z+x2.w);
    s3 += (x3.x+x3.y)+(x3.z+x3.w);
    p00 += x0.x*x0.x+x0.y*x0.y+x0.z*x0.z+x0.w*x0.w;
    p01 += x0.x*x1.x+x0.y*x1.y+x0.z*x1.z+x0.w*x1.w;
    p02 += x0.x*x2.x+x0.y*x2.y+x0.z*x2.z+x0.w*x2.w;
    p03 += x0.x*x3.x+x0.y*x3.y+x0.z*x3.z+x0.w*x3.w;
    p11 += x1.x*x1.x+x1.y*x1.y+x1.z*x1.z+x1.w*x1.w;
    p12 += x1.x*x2.x+x1.y*x2.y+x1.z*x2.z+x1.w*x2.w;
    p13 += x1.x*x3.x+x1.y*x3.y+x1.z*x3.z+x1.w*x3.w;
    p22 += x2.x*x2.x+x2.y*x2.y+x2.z*x2.z+x2.w*x2.w;
    p23 += x2.x*x3.x+x2.y*x3.y+x2.z*x3.z+x2.w*x3.w;
    p33 += x3.x*x3.x+x3.y*x3.y+x3.z*x3.z+x3.w*x3.w;
  }
  float vals[14] = {s0,s1,s2,s3,p00,p01,p02,p03,p11,p12,p13,p22,p23,p33};
  __shared__ float red[4][14];
  int lane = tid & 63, wv = tid >> 6;
  #pragma unroll
  for (int j=0;j<14;j++){
    float v = vals[j];
    #pragma unroll
    for (int o=32;o>0;o>>=1) v += __shfl_down(v,o,64);
    if (lane==0) red[wv][j]=v;
  }
  __syncthreads();
  if (tid<14) part[((size_t)b*64+blk)*16 + tid] = red[0][tid]+red[1][tid]+red[2][tid]+red[3][tid];
}

// ---- k_attW (unchanged) ---------------------------------------------------
__global__ __launch_bounds__(256) void k_attW(const float* __restrict__ part,
        const float* __restrict__ alpha, const float* __restrict__ gamma, const float* __restrict__ beta,
        int iblk, const float* __restrict__ wf1, float* __restrict__ Weff){
  const int b = blockIdx.x, tid = threadIdx.x;
  __shared__ float st[14];
  __shared__ float att[16];
  if (tid<14){
    float t=0;
    for (int blk=0;blk<64;blk++) t += part[((size_t)b*64+blk)*16 + tid];
    st[tid]=t;
  }
  __syncthreads();
  if (tid==0){
    const float M = 1638400.f;
    float s[4] = {st[0],st[1],st[2],st[3]};
    float S[4][4];
    S[0][0]=st[4];  S[0][1]=S[1][0]=st[5];  S[0][2]=S[2][0]=st[6];  S[0][3]=S[3][0]=st[7];
    S[1][1]=st[8];  S[1][2]=S[2][1]=st[9];  S[1][3]=S[3][1]=st[10];
    S[2][2]=st[11]; S[2][3]=S[3][2]=st[12]; S[3][3]=st[13];
    float al=alpha[iblk], ga=gamma[iblk], be=beta[iblk];
    float scale = al/(M-1.f);
    float cov[4][4], ss=0.f;
    for (int n=0;n<4;n++) for (int k=0;k<4;k++){
      float c = (S[n][k] - s[n]*s[k]/M)*scale;
      cov[n][k]=c; ss += c*c;
    }
    float rms = sqrtf(ss/16.f + 1e-5f);
    for (int n=0;n<4;n++) for (int k=0;k<4;k++){
      float g = ga*cov[n][k]/rms + be;
      att[n*4+k] = g/(1.f+expf(-g));
    }
  }
  __syncthreads();
  for (int idx=tid; idx<16384; idx+=256){
    int co=idx>>8, kc=idx&255, k=kc>>6, c=kc&63;
    float v = wf1[co*256+kc];
    #pragma unroll
    for (int n=0;n<4;n++) v += att[n*4+k]*wf1[co*256+n*64+c];
    Weff[(size_t)b*16384+idx] = v;
  }
}

// ---------------- fuse1 (unchanged) ----------------------------------------
__global__ __launch_bounds__(256) void k_fuse1(const float* b0, const float* __restrict__ b1,
                                               const float* __restrict__ b2, const float* __restrict__ b3,
                                               const float* __restrict__ Weff, float* y64){
  const int tile = blockIdx.x, b = blockIdx.y;
  const int px0 = tile*64;
  const int tid = threadIdx.x;
  const int ti = tid >> 4, tj = tid & 15;
  __shared__ float xs[64][68];
  __shared__ float wt[64][68];
  float acc[4][4];
  #pragma unroll
  for (int i=0;i<4;i++)
    #pragma unroll
    for (int j=0;j<4;j++) acc[i][j]=0.f;
  const float* bptr[4] = {b0,b1,b2,b3};
  for (int kb=0; kb<4; kb++){
    const float* xbk = bptr[kb] + (size_t)b*1638400 + px0;
    const float* wb = Weff + (size_t)b*16384 + kb*64;
    __syncthreads();
    for (int idx=tid; idx<4096; idx+=256){
      int kc=idx>>6, px=idx&63;
      xs[kc][px] = xbk[(size_t)kc*25600 + px];
    }
    for (int idx=tid; idx<4096; idx+=256){
      int co=idx>>6, k2=idx&63;
      wt[k2][co] = wb[co*256 + k2];
    }
    __syncthreads();
    for (int k2=0;k2<64;k2++){
      float4 a = *(const float4*)&wt[k2][ti*4];
      float4 v = *(const float4*)&xs[k2][tj*4];
      acc[0][0]+=a.x*v.x; acc[0][1]+=a.x*v.y; acc[0][2]+=a.x*v.z; acc[0][3]+=a.x*v.w;
      acc[1][0]+=a.y*v.x; acc[1][1]+=a.y*v.y; acc[1][2]+=a.y*v.z; acc[1][3]+=a.y*v.w;
      acc[2][0]+=a.z*v.x; acc[2][1]+=a.z*v.y; acc[2][2]+=a.z*v.z; acc[2][3]+=a.z*v.w;
      acc[3][0]+=a.w*v.x; acc[3][1]+=a.w*v.y; acc[3][2]+=a.w*v.z; acc[3][3]+=a.w*v.w;
    }
  }
  #pragma unroll
  for (int i=0;i<4;i++){
    int co = ti*4 + i;
    float4 o = make_float4(lrelu(acc[i][0]), lrelu(acc[i][1]), lrelu(acc[i][2]), lrelu(acc[i][3]));
    *(float4*)(y64 + ((size_t)(b*64+co))*25600 + px0 + tj*4) = o;
  }
}

// ---------------- fuse2: dilated 3x3 (dil 5, pad 5) + residual ------------
// Wave-synchronous: wave wv owns pixel rows {2wv,2wv+1,2wv+8,2wv+9}; stages its 12 tap
// rows (local deltas {0,1,5,6,8,9,10,11,13,14,18,19}+2wv; 48-col halo) into private
// wl[wv]; thread taps at slots lrl+{0,2,6} (k=0) and lrl+{4,8,10} (k=1). No barriers.
// grid: 1600 1-D swizzled (200 tiles x 8 cogroups of 8co).
template<int FINAL>
__global__ __launch_bounds__(256) void k_fuse2(const float* __restrict__ y64, const float* resid,
                                               const float* __restrict__ w, float* outp){
  const int P = blockIdx.x;
  const int within = P >> 3, cog = within & 7, tsel = within >> 3;
  const int tg = (P & 7)*25 + tsel;            // 0..199
  const int b = tg / 50, tile = tg % 50;
  const int th0 = (tile/5)*16, tw0 = (tile%5)*32;
  const int tid = threadIdx.x;
  const int wv = tid >> 6, lane = tid & 63;
  __shared__ float wl[4][2][576];   // per-wave: 12 row-slots x 48 cols, 2 bufs
  for (int i=lane; i<1152; i+=64) ((float*)wl[wv])[i] = 0.f;
  float acc[2][8];
  #pragma unroll
  for (int k=0;k<2;k++)
    #pragma unroll
    for (int c2=0;c2<8;c2++) acc[k][c2]=0.f;
  const float* src = y64 + (size_t)b*1638400;
  // staging: 144 slots (12 rows x 12 float4); lane handles m = lane, lane+64, lane+128(<144)
  int sdst[3], soff[3];
  bool sok[3];
  #pragma unroll
  for (int j=0;j<3;j++){
    int m = lane + j*64;
    bool act = m < 144;
    int mm = act ? m : 0;
    int srow = mm/12, q = mm - srow*12;
    int dlt = srow + 3*(srow>=2) + (srow>=4) + (srow>=8) + 3*(srow>=10);  // {0,1,5,6,8,9,10,11,13,14,18,19}
    int gh = th0 - 5 + 2*wv + dlt, gw = tw0 - 8 + q*4;
    sok[j] = act && ((unsigned)gh < 160u) && ((unsigned)gw < 160u);
    soff[j] = gh*160 + gw;
    sdst[j] = srow*48 + q*4;
  }
  // prologue: stage ci=0 (OOB/inactive slots stay zero forever)
  #pragma unroll
  for (int j=0;j<3;j++)
    if (sok[j]) *(float4*)&wl[wv][0][sdst[j]] = *(const float4*)(src + soff[j]);
  const int lrl = (tid >> 5) & 1, c = tid & 31;
  const int t0base = lrl*48 + c + 3;
  for (int ci=0; ci<64; ci++){
    float4 n0, n1, n2;
    if (ci < 63){
      const float* sN = src + (size_t)(ci+1)*25600;
      if (sok[0]) n0 = *(const float4*)(sN + soff[0]);
      if (sok[1]) n1 = *(const float4*)(sN + soff[1]);
      if (sok[2]) n2 = *(const float4*)(sN + soff[2]);
    }
    const float* Pb = wl[wv][ci & 1];
    float t0[9], t1[9];
    {
      const float* pp = &Pb[t0base];
      t0[0]=pp[0];        t0[1]=pp[5];        t0[2]=pp[10];       // slot lrl    (row lr)
      t0[3]=pp[2*48];     t0[4]=pp[2*48+5];   t0[5]=pp[2*48+10];  // slot lrl+2  (row lr+5)
      t0[6]=pp[6*48];     t0[7]=pp[6*48+5];   t0[8]=pp[6*48+10];  // slot lrl+6  (row lr+10)
      t1[0]=pp[4*48];     t1[1]=pp[4*48+5];   t1[2]=pp[4*48+10];  // slot lrl+4  (row lr+8)
      t1[3]=pp[8*48];     t1[4]=pp[8*48+5];   t1[5]=pp[8*48+10];  // slot lrl+8  (row lr+13)
      t1[6]=pp[10*48];    t1[7]=pp[10*48+5];  t1[8]=pp[10*48+10]; // slot lrl+10 (row lr+18)
    }
    const float* wrow = w + ci*576 + cog*72;   // repacked: 72 contiguous dwords
    #pragma unroll
    for (int co=0;co<8;co++){
      const float* wp = wrow + co*9;
      float w0=wp[0],w1=wp[1],w2=wp[2],w3=wp[3],w4=wp[4],w5=wp[5],w6=wp[6],w7=wp[7],w8=wp[8];
      acc[0][co] += t0[0]*w0+t0[1]*w1+t0[2]*w2+t0[3]*w3+t0[4]*w4
                  + t0[5]*w5+t0[6]*w6+t0[7]*w7+t0[8]*w8;
      acc[1][co] += t1[0]*w0+t1[1]*w1+t1[2]*w2+t1[3]*w3+t1[4]*w4
                  + t1[5]*w5+t1[6]*w6+t1[7]*w7+t1[8]*w8;
    }
    if (ci < 63){
      float* Q = wl[wv][(ci+1)&1];
      if (sok[0]) *(float4*)&Q[sdst[0]] = n0;
      if (sok[1]) *(float4*)&Q[sdst[1]] = n1;
      if (sok[2]) *(float4*)&Q[sdst[2]] = n2;
    }
  }
  #pragma unroll
  for (int k=0;k<2;k++){
    int h = th0 + 2*wv + lrl + k*8, wq = tw0 + c;
    #pragma unroll
    for (int co=0;co<8;co++){
      int cg = cog*8 + co;
      size_t base = ((size_t)(b*64+cg)*160 + h)*160 + wq;
      outp[base] = acc[k][co] + resid[base];
    }
  }
}

extern "C" void kernel_launch(void* const* d_in, const int* in_sizes, int n_in,
                              void* d_out, int out_size, void* d_ws, size_t ws_size,
                              hipStream_t stream){
  const float* x    = (const float*)d_in[0];
  const float* x1   = (const float*)d_in[1];
  const float* wspa = (const float*)d_in[2];
  const float* wang = (const float*)d_in[3];
  const float* we1  = (const float*)d_in[4];
  const float* we2  = (const float*)d_in[5];
  const float* al   = (const float*)d_in[6];
  const float* ga   = (const float*)d_in[7];
  const float* be   = (const float*)d_in[8];
  const float* wf1  = (const float*)d_in[9];
  const float* wf2  = (const float*)d_in[10];

  char* ws = (char*)d_ws;
  const size_t SLOT = 26214400;
  float* A  = (float*)(ws);          // MacPI buf (in-place residual chain)
  float* Bv = (float*)(ws +   SLOT); // B1 input / branchV / newB1
  float* T1 = (float*)(ws + 2*SLOT); // branchSpa -> y64 in-place
  float* T2 = (float*)(ws + 3*SLOT); // epiV tmp -> branchAng
  float* part = (float*)(ws + 4*SLOT);            // 4*64*16 f32 (16KB)
  float* Weff = (float*)(ws + 4*SLOT + 16384);    // 4*64*256 f32 (256KB)
  float* Wrep = (float*)(ws + 4*SLOT + 16384 + 262144);  // 3*4*36864 f32 (1.7MB)
  float* WspaR = Wrep;
  float* WangR = Wrep + 147456;
  float* Wf2R  = Wrep + 2*147456;
  float* D = (float*)d_out;          // A^T / branchH scratch; final output at the end

  k_wrep<<<1728,256,0,stream>>>(wspa, wang, wf2, Wrep);

  for (int i=0;i<4;i++){
    const float* Asrc  = (i==0) ? x  : (const float*)A;
    const float* B1src = (i==0) ? x1 : (const float*)Bv;
    k_permV<<<dim3(256,25),256,0,stream>>>(Asrc, D);                             // D = Asrc^T
    k_epi<<<1280,320,0,stream>>>(D, we1 + (size_t)i*61440, we2 + (size_t)i*20480, T2);   // epiV (tmp layout)
    k_spa<<<1600,256,0,stream>>>(B1src, WspaR + (size_t)i*36864, T1);
    k_permV<<<dim3(256,25),256,0,stream>>>(T2, Bv);                              // branchV
    k_ang<<<1024,320,0,stream>>>(Asrc, WangR + (size_t)i*36864, T2);
    k_epi<<<1280,320,0,stream>>>(Asrc, we1 + (size_t)i*61440, we2 + (size_t)i*20480, D); // branchH
    k_red<<<dim3(64,4),256,0,stream>>>(T1, T2, D, Bv, part);
    k_attW<<<4,256,0,stream>>>(part, al, ga, be, i, wf1 + (size_t)i*16384, Weff);
    k_fuse1<<<dim3(400,4),256,0,stream>>>(T1, T2, D, Bv, Weff, T1);
    if (i<3){
      k_fuse2<0><<<1600,256,0,stream>>>(T1, Asrc, Wf2R + (size_t)i*36864, A);
      k_permM<<<8192,256,0,stream>>>(A, Bv);
    } else {
      k_fuse2<1><<<1600,256,0,stream>>>(T1, Asrc, Wf2R + (size_t)i*36864, D);
    }
  }
}

// Round 15
// 2725.427 us; speedup vs baseline: 1.0766x; 1.0056x over previous
//
#include <hip/hip_runtime.h>

__device__ __forceinline__ float lrelu(float v){ return v >= 0.f ? v : 0.1f*v; }

// Dims: B=4, C=64, H=W=160, HW=25600, per-tensor (B,64,160,160) f32: batch stride 1,638,400
// ws: 4 f32 slots x 26,214,400 B (A, Bv, T1, T2) + part/Weff/Wrep tail. branchH in d_out.
// Lessons: BK=2 regresses; co=16 regresses; conflicts fixed; repack ~neutral; barrier
// removal (wave-sync) neutral-to-positive; grid>=1280 critical.
// R15: spa/fuse2 as 1-WAVE BLOCKS (64 thr), grid 6400: each R14 wave -> own block.
// LDS 4.6/1.9KB -> up to 32 blocks/CU; dense latency cover for per-wave VMEM chains.

// ---------------- weight repack: [4][64co][64ci][9] -> [4][64ci][64co][9], 3 tensors
__global__ __launch_bounds__(256) void k_wrep(const float* __restrict__ wspa, const float* __restrict__ wang,
                                              const float* __restrict__ wf2, float* __restrict__ outp){
  int id = blockIdx.x*256 + threadIdx.x;       // < 442368
  int t = id / 147456, r = id - t*147456;
  int i = r / 36864,  e = r - i*36864;
  int ci = e / 576,   r3 = e - ci*576;
  int co = r3 / 9,    j = r3 - co*9;
  const float* src = (t==0 ? wspa : (t==1 ? wang : wf2));
  outp[id] = src[(size_t)i*36864 + co*576 + ci*9 + j];
}

// ---------------- spa: per-view 3x3 conv (zero pad at view edges) ----------
// 1-wave blocks: block owns 4 pixel rows (view rows th0+4wv..th0+4wv+3); stages its
// 6 tap rows into private LDS; no barriers. grid 6400 = 8xcd x (25tsel x 8cog x 4wv).
__global__ __launch_bounds__(64) void k_spa(const float* __restrict__ buf1, const float* __restrict__ w,
                                            float* __restrict__ out){
  const int P = blockIdx.x;
  const int xcd = P & 7, within = P >> 3;
  const int wv = within & 3, cog = (within >> 2) & 7, tsel = within >> 5;  // tsel 0..24
  const int tg = xcd*25 + tsel;                // 0..199
  const int b = tg / 50, r2 = tg % 50;
  const int view = r2 >> 1, half = r2 & 1;
  const int bi = view / 5, bj = view % 5;
  const int th0 = half*16;
  const int lane = threadIdx.x;
  __shared__ float wl[2][240];      // 6 rows x 40 (data cols 4..35, zeros 3/36), 2 bufs
  for (int i=lane; i<480; i+=64) ((float*)wl)[i] = 0.f;
  float acc[2][8];
  #pragma unroll
  for (int k=0;k<2;k++)
    #pragma unroll
    for (int c2=0;c2<8;c2++) acc[k][c2]=0.f;
  const float* src = buf1 + (size_t)b*1638400 + bi*32*160 + bj*32;
  // staging: 48 slots (6 rows x 8 float4); lane<48 handles one
  const int srow = lane >> 3, sq = (lane & 7)*4;
  const int vr = th0 + 4*wv - 1 + srow;
  const bool rowok = (lane < 48) && ((unsigned)vr < 32u);
  const int dst = srow*40 + 4 + sq;
  if (rowok)
    *(float4*)&wl[0][dst] = *(const float4*)(src + vr*160 + sq);
  const int lrl = (lane >> 5) & 1, c = lane & 31;
  for (int ci=0; ci<64; ci++){
    float4 nx;
    const bool ld = rowok && (ci < 63);
    if (ld) nx = *(const float4*)(src + (size_t)(ci+1)*25600 + vr*160 + sq);
    const float* Pb = wl[ci & 1];
    float g[4][3];
    {
      const float* pp = &Pb[(2*lrl)*40 + c + 3];
      g[0][0]=pp[0];   g[0][1]=pp[1];   g[0][2]=pp[2];
      g[1][0]=pp[40];  g[1][1]=pp[41];  g[1][2]=pp[42];
      g[2][0]=pp[80];  g[2][1]=pp[81];  g[2][2]=pp[82];
      g[3][0]=pp[120]; g[3][1]=pp[121]; g[3][2]=pp[122];
    }
    const float* wrow = w + ci*576 + cog*72;   // repacked: 72 contiguous dwords
    #pragma unroll
    for (int co=0;co<8;co++){
      const float* wp = wrow + co*9;
      float w0=wp[0],w1=wp[1],w2=wp[2],w3=wp[3],w4=wp[4],w5=wp[5],w6=wp[6],w7=wp[7],w8=wp[8];
      acc[0][co] += g[0][0]*w0+g[0][1]*w1+g[0][2]*w2+g[1][0]*w3+g[1][1]*w4
                  + g[1][2]*w5+g[2][0]*w6+g[2][1]*w7+g[2][2]*w8;
      acc[1][co] += g[1][0]*w0+g[1][1]*w1+g[1][2]*w2+g[2][0]*w3+g[2][1]*w4
                  + g[2][2]*w5+g[3][0]*w6+g[3][1]*w7+g[3][2]*w8;
    }
    if (ld) *(float4*)&wl[(ci+1)&1][dst] = nx;
  }
  #pragma unroll
  for (int k=0;k<2;k++){
    int si = th0 + 4*wv + 2*lrl + k;
    int h = si*5 + bi, wq = c*5 + bj;
    #pragma unroll
    for (int co=0;co<8;co++){
      int ch = b*64 + cog*8 + co;
      out[(size_t)ch*25600 + h*160 + wq] = lrelu(acc[k][co]);
    }
  }
}

// ---------------- ang: per-macropixel (5x5) 3x3 conv, row-per-thread ------
// (unchanged from R13: barrier version, stride-164, repacked weights)
__global__ __launch_bounds__(320) void k_ang(const float* __restrict__ bufA, const float* __restrict__ w,
                                             float* __restrict__ out){
  const int P = blockIdx.x;
  const int within = P >> 3, cog = within & 15, tsel = within >> 4;
  const int tg = (P & 7)*8 + tsel;             // 0..63
  const int b = tg >> 4, mip = tg & 15;
  const int tid = threadIdx.x;
  __shared__ float lds[2][2296];
  for (int i=tid; i<2*2296; i+=320) ((float*)lds)[i] = 0.f;

  const int u = tid >> 6, mi_l = (tid >> 5) & 1, mp = tid & 31;
  int ro[3];
  #pragma unroll
  for (int du=0; du<3; du++)
    ro[du] = mi_l*1148 + (u+du)*164 + mp*5;
  const bool st1 = tid < 80;
  const int rr0 = tid/40,       q0 = tid%40;
  const int rr1 = (tid+320)/40, q1 = (tid+320)%40;
  const int dst0 = (rr0/5)*1148 + (1 + rr0%5)*164 + q0*4;
  const int dst1 = (rr1/5)*1148 + (1 + rr1%5)*164 + q1*4;
  const float* src = bufA + (size_t)b*1638400 + (size_t)(mip*10)*160;

  float acc[4][5];
  #pragma unroll
  for (int co=0;co<4;co++)
    #pragma unroll
    for (int v=0;v<5;v++) acc[co][v]=0.f;

  __syncthreads();
  {
    *(float4*)&lds[0][dst0] = *(const float4*)(src + rr0*160 + q0*4);
    if (st1)
      *(float4*)&lds[0][dst1] = *(const float4*)(src + rr1*160 + q1*4);
  }
  __syncthreads();
  for (int ci=0; ci<64; ci++){
    float4 n0, n1;
    if (ci < 63){
      n0 = *(const float4*)(src + (size_t)(ci+1)*25600 + rr0*160 + q0*4);
      if (st1) n1 = *(const float4*)(src + (size_t)(ci+1)*25600 + rr1*160 + q1*4);
    }
    const float* Pb = lds[ci & 1];
    float c[3][5];
    #pragma unroll
    for (int du=0;du<3;du++){
      const float* rp = &Pb[ro[du]];
      c[du][0]=rp[0]; c[du][1]=rp[1]; c[du][2]=rp[2]; c[du][3]=rp[3]; c[du][4]=rp[4];
    }
    const float* wrow = w + ci*576 + cog*36;
    #pragma unroll
    for (int co=0;co<4;co++){
      const float* wp = wrow + co*9;
      float w0=wp[0],w1=wp[1],w2=wp[2],w3=wp[3],w4=wp[4],w5=wp[5],w6=wp[6],w7=wp[7],w8=wp[8];
      acc[co][0] += c[0][0]*w1 + c[0][1]*w2
                  + c[1][0]*w4 + c[1][1]*w5
                  + c[2][0]*w7 + c[2][1]*w8;
      acc[co][1] += c[0][0]*w0 + c[0][1]*w1 + c[0][2]*w2
                  + c[1][0]*w3 + c[1][1]*w4 + c[1][2]*w5
                  + c[2][0]*w6 + c[2][1]*w7 + c[2][2]*w8;
      acc[co][2] += c[0][1]*w0 + c[0][2]*w1 + c[0][3]*w2
                  + c[1][1]*w3 + c[1][2]*w4 + c[1][3]*w5
                  + c[2][1]*w6 + c[2][2]*w7 + c[2][3]*w8;
      acc[co][3] += c[0][2]*w0 + c[0][3]*w1 + c[0][4]*w2
                  + c[1][2]*w3 + c[1][3]*w4 + c[1][4]*w5
                  + c[2][2]*w6 + c[2][3]*w7 + c[2][4]*w8;
      acc[co][4] += c[0][3]*w0 + c[0][4]*w1
                  + c[1][3]*w3 + c[1][4]*w4
                  + c[2][3]*w6 + c[2][4]*w7;
    }
    if (ci < 63){
      float* Q = lds[(ci+1)&1];
      *(float4*)&Q[dst0] = n0;
      if (st1) *(float4*)&Q[dst1] = n1;
    }
    __syncthreads();
  }
  const int h = (mip*2 + mi_l)*5 + u;
  const int wc0 = mp*5;
  #pragma unroll
  for (int co=0;co<4;co++){
    int ch = b*64 + cog*4 + co;
    float* op = out + (size_t)ch*25600 + (size_t)h*160 + wc0;
    op[0]=lrelu(acc[co][0]); op[1]=lrelu(acc[co][1]); op[2]=lrelu(acc[co][2]);
    op[3]=lrelu(acc[co][3]); op[4]=lrelu(acc[co][4]);
  }
}

// ---------------- fused EPI (unchanged from R13) --------------------------
__global__ __launch_bounds__(320) void k_epi(const float* __restrict__ bufA, const float* __restrict__ we1,
                                             const float* __restrict__ we2, float* __restrict__ out){
  const int bb = blockIdx.x >> 1, half = blockIdx.x & 1;
  const int b = bb / 160, hw = bb % 160;
  const int tid = threadIdx.x;
  __shared__ float rowp[64*96];
  __shared__ float y1s[64*16];
  const int lofs = half ? 0 : 8;
  const int xofs = half ? 72 : 0;
  for (int ft=tid; ft<1408; ft+=320){
    int ci = ft/22, q = ft - ci*22;
    *(float4*)&rowp[ci*96 + lofs + q*4] =
      *(const float4*)(bufA + (size_t)b*1638400 + (size_t)ci*25600 + (size_t)hw*160 + xofs + q*4);
  }
  for (int idx=tid; idx<512; idx+=320){
    int ci = idx>>3, j = idx&7;
    rowp[ci*96 + (half ? 88+j : j)] = 0.f;
  }
  __syncthreads();
  if (tid < 256){
    const int co = tid >> 2, wvl0 = (tid & 3)*4;
    const int a0 = 2 + wvl0*5;
    float acc[4];
    #pragma unroll
    for (int j=0;j<4;j++) acc[j]=0.f;
    const float* wp0 = we1 + (size_t)co*960;
    for (int ci=0; ci<64; ci++){
      float fl[32];
      const float* rp = &rowp[ci*96 + a0];
      #pragma unroll
      for (int m=0;m<16;m++) *(float2*)&fl[2*m] = *(const float2*)&rp[2*m];
      const float* wp = wp0 + ci*15;
      #pragma unroll
      for (int t=0;t<15;t++){
        float wt = wp[t];
        #pragma unroll
        for (int j=0;j<4;j++) acc[j] += fl[1 + j*5 + t]*wt;
      }
    }
    #pragma unroll
    for (int j=0;j<4;j++) y1s[co*16 + wvl0 + j] = lrelu(acc[j]);
  }
  __syncthreads();
  {
    const int oc = tid, kk = oc >> 6, c = oc & 63;
    float a2[16];
    #pragma unroll
    for (int wv2=0;wv2<16;wv2++) a2[wv2]=0.f;
    const float* wp = we2 + (size_t)oc*64;
    for (int ci=0; ci<64; ci++){
      float wt = wp[ci];
      const float* yp = &y1s[ci*16];
      #pragma unroll
      for (int wv2=0; wv2<16; wv2++) a2[wv2] += yp[wv2]*wt;
    }
    float* y2s = rowp;
    #pragma unroll
    for (int wv2=0; wv2<16; wv2++) y2s[c*84 + wv2*5 + kk] = lrelu(a2[wv2]);
  }
  __syncthreads();
  {
    const float* y2s = rowp;
    for (int k=0;k<4;k++){
      int f = (tid + k*320)*4;
      int c = f/80, rr = f - c*80;
      *(float4*)(out + (size_t)(b*64+c)*25600 + (size_t)hw*160 + half*80 + rr)
        = *(const float4*)&y2s[c*84+rr];
    }
  }
}

// ---------------- permV (unchanged) ----------------------------------------
__global__ __launch_bounds__(256) void k_permV(const float* __restrict__ tmp, float* __restrict__ dst){
  const int bc = blockIdx.x;
  const int ti = blockIdx.y / 5, tj = blockIdx.y % 5;
  const int hw0 = ti*32, r0 = tj*32;
  const int lx = threadIdx.x & 31, ly = threadIdx.x >> 5;
  __shared__ float tile[32][33];
  const float* in = tmp + (size_t)bc*25600;
  float* outp = dst + (size_t)bc*25600;
  for (int yy=ly; yy<32; yy+=8)
    tile[yy][lx] = in[(size_t)(hw0+yy)*160 + r0 + lx];
  __syncthreads();
  for (int yy=ly; yy<32; yy+=8)
    outp[(size_t)(r0+yy)*160 + hw0 + lx] = tile[lx][yy];
}

// ---------------- permM (unchanged) ----------------------------------------
__global__ __launch_bounds__(256) void k_permM(const float* __restrict__ A, float* __restrict__ dst){
  const int bc = blockIdx.x >> 5, hh = blockIdx.x & 31;
  const int tid = threadIdx.x;
  __shared__ float rows[5*160];
  const float* in = A + (size_t)bc*25600;
  if (tid < 200){
    int ai = tid/40, q = (tid - ai*40)*4;
    *(float4*)&rows[ai*160 + q] = *(const float4*)(in + (size_t)(ai*32+hh)*160 + q);
  }
  __syncthreads();
  float* outp = dst + (size_t)bc*25600 + (size_t)hh*800;
  for (int t=tid; t<800; t+=256){
    int ww = t/25, r2 = t - ww*25, ai = r2/5, aj = r2 - ai*5;
    outp[t] = rows[ai*160 + aj*32 + ww];
  }
}

// ---------------- k_red (unchanged) ----------------------------------------
__global__ __launch_bounds__(256) void k_red(const float* __restrict__ b0, const float* __restrict__ b1,
                                             const float* __restrict__ b2, const float* __restrict__ b3,
                                             float* __restrict__ part){
  const int b = blockIdx.y, blk = blockIdx.x;
  const int tid = threadIdx.x;
  const size_t off = (size_t)b*1638400 + (size_t)blk*25600;
  float s0=0,s1=0,s2=0,s3=0;
  float p00=0,p01=0,p02=0,p03=0,p11=0,p12=0,p13=0,p22=0,p23=0,p33=0;
  for (int it=0; it<25; it++){
    size_t m = off + it*1024 + tid*4;
    float4 x0 = *(const float4*)(b0+m);
    float4 x1 = *(const float4*)(b1+m);
    float4 x2 = *(const float4*)(b2+m);
    float4 x3 = *(const float4*)(b3+m);
    s0 += (x0.x+x0.y)+(x0.z+x0.w);
    s1 += (x1.x+x1.y)+(x1.z+x1.w);
    s2 += (x2.x+x2.y)+(x2.z+x2.w);
    s3 += (x3.x+x3.y)+(x3.z+x3.w);
    p00 += x0.x*x0.x+x0.y*x0.y+x0.z*x0.z+x0.w*x0.w;
    p01 += x0.x*x1.x+x0.y*x1.y+x0.z*x1.z+x0.w*x1.w;
    p02 += x0.x*x2.x+x0.y*x2.y+x0.z*x2.z+x0.w*x2.w;
    p03 += x0.x*x3.x+x0.y*x3.y+x0.z*x3.z+x0.w*x3.w;
    p11 += x1.x*x1.x+x1.y*x1.y+x1.z*x1.z+x1.w*x1.w;
    p12 += x1.x*x2.x+x1.y*x2.y+x1.z*x2.z+x1.w*x2.w;
    p13 += x1.x*x3.x+x1.y*x3.y+x1.z*x3.z+x1.w*x3.w;
    p22 += x2.x*x2.x+x2.y*x2.y+x2.z*x2.z+x2.w*x2.w;
    p23 += x2.x*x3.x+x2.y*x3.y+x2.z*x3.z+x2.w*x3.w;
    p33 += x3.x*x3.x+x3.y*x3.y+x3.z*x3.z+x3.w*x3.w;
  }
  float vals[14] = {s0,s1,s2,s3,p00,p01,p02,p03,p11,p12,p13,p22,p23,p33};
  __shared__ float red[4][14];
  int lane = tid & 63, wv = tid >> 6;
  #pragma unroll
  for (int j=0;j<14;j++){
    float v = vals[j];
    #pragma unroll
    for (int o=32;o>0;o>>=1) v += __shfl_down(v,o,64);
    if (lane==0) red[wv][j]=v;
  }
  __syncthreads();
  if (tid<14) part[((size_t)b*64+blk)*16 + tid] = red[0][tid]+red[1][tid]+red[2][tid]+red[3][tid];
}

// ---- k_attW (unchanged) ---------------------------------------------------
__global__ __launch_bounds__(256) void k_attW(const float* __restrict__ part,
        const float* __restrict__ alpha, const float* __restrict__ gamma, const float* __restrict__ beta,
        int iblk, const float* __restrict__ wf1, float* __restrict__ Weff){
  const int b = blockIdx.x, tid = threadIdx.x;
  __shared__ float st[14];
  __shared__ float att[16];
  if (tid<14){
    float t=0;
    for (int blk=0;blk<64;blk++) t += part[((size_t)b*64+blk)*16 + tid];
    st[tid]=t;
  }
  __syncthreads();
  if (tid==0){
    const float M = 1638400.f;
    float s[4] = {st[0],st[1],st[2],st[3]};
    float S[4][4];
    S[0][0]=st[4];  S[0][1]=S[1][0]=st[5];  S[0][2]=S[2][0]=st[6];  S[0][3]=S[3][0]=st[7];
    S[1][1]=st[8];  S[1][2]=S[2][1]=st[9];  S[1][3]=S[3][1]=st[10];
    S[2][2]=st[11]; S[2][3]=S[3][2]=st[12]; S[3][3]=st[13];
    float al=alpha[iblk], ga=gamma[iblk], be=beta[iblk];
    float scale = al/(M-1.f);
    float cov[4][4], ss=0.f;
    for (int n=0;n<4;n++) for (int k=0;k<4;k++){
      float c = (S[n][k] - s[n]*s[k]/M)*scale;
      cov[n][k]=c; ss += c*c;
    }
    float rms = sqrtf(ss/16.f + 1e-5f);
    for (int n=0;n<4;n++) for (int k=0;k<4;k++){
      float g = ga*cov[n][k]/rms + be;
      att[n*4+k] = g/(1.f+expf(-g));
    }
  }
  __syncthreads();
  for (int idx=tid; idx<16384; idx+=256){
    int co=idx>>8, kc=idx&255, k=kc>>6, c=kc&63;
    float v = wf1[co*256+kc];
    #pragma unroll
    for (int n=0;n<4;n++) v += att[n*4+k]*wf1[co*256+n*64+c];
    Weff[(size_t)b*16384+idx] = v;
  }
}

// ---------------- fuse1 (unchanged) ----------------------------------------
__global__ __launch_bounds__(256) void k_fuse1(const float* b0, const float* __restrict__ b1,
                                               const float* __restrict__ b2, const float* __restrict__ b3,
                                               const float* __restrict__ Weff, float* y64){
  const int tile = blockIdx.x, b = blockIdx.y;
  const int px0 = tile*64;
  const int tid = threadIdx.x;
  const int ti = tid >> 4, tj = tid & 15;
  __shared__ float xs[64][68];
  __shared__ float wt[64][68];
  float acc[4][4];
  #pragma unroll
  for (int i=0;i<4;i++)
    #pragma unroll
    for (int j=0;j<4;j++) acc[i][j]=0.f;
  const float* bptr[4] = {b0,b1,b2,b3};
  for (int kb=0; kb<4; kb++){
    const float* xbk = bptr[kb] + (size_t)b*1638400 + px0;
    const float* wb = Weff + (size_t)b*16384 + kb*64;
    __syncthreads();
    for (int idx=tid; idx<4096; idx+=256){
      int kc=idx>>6, px=idx&63;
      xs[kc][px] = xbk[(size_t)kc*25600 + px];
    }
    for (int idx=tid; idx<4096; idx+=256){
      int co=idx>>6, k2=idx&63;
      wt[k2][co] = wb[co*256 + k2];
    }
    __syncthreads();
    for (int k2=0;k2<64;k2++){
      float4 a = *(const float4*)&wt[k2][ti*4];
      float4 v = *(const float4*)&xs[k2][tj*4];
      acc[0][0]+=a.x*v.x; acc[0][1]+=a.x*v.y; acc[0][2]+=a.x*v.z; acc[0][3]+=a.x*v.w;
      acc[1][0]+=a.y*v.x; acc[1][1]+=a.y*v.y; acc[1][2]+=a.y*v.z; acc[1][3]+=a.y*v.w;
      acc[2][0]+=a.z*v.x; acc[2][1]+=a.z*v.y; acc[2][2]+=a.z*v.z; acc[2][3]+=a.z*v.w;
      acc[3][0]+=a.w*v.x; acc[3][1]+=a.w*v.y; acc[3][2]+=a.w*v.z; acc[3][3]+=a.w*v.w;
    }
  }
  #pragma unroll
  for (int i=0;i<4;i++){
    int co = ti*4 + i;
    float4 o = make_float4(lrelu(acc[i][0]), lrelu(acc[i][1]), lrelu(acc[i][2]), lrelu(acc[i][3]));
    *(float4*)(y64 + ((size_t)(b*64+co))*25600 + px0 + tj*4) = o;
  }
}

// ---------------- fuse2: dilated 3x3 (dil 5, pad 5) + residual ------------
// 1-wave blocks: block owns pixel rows {2wv,2wv+1,2wv+8,2wv+9} of a 16x32 tile; stages
// its 12 tap rows (deltas {0,1,5,6,8,9,10,11,13,14,18,19}+2wv; 48-col halo) into private
// LDS; taps at slots lrl+{0,2,6} (k=0) / lrl+{4,8,10} (k=1). No barriers.
// grid 6400 = 8xcd x (25tsel x 8cog x 4wv).
template<int FINAL>
__global__ __launch_bounds__(64) void k_fuse2(const float* __restrict__ y64, const float* resid,
                                              const float* __restrict__ w, float* outp){
  const int P = blockIdx.x;
  const int xcd = P & 7, within = P >> 3;
  const int wv = within & 3, cog = (within >> 2) & 7, tsel = within >> 5;  // tsel 0..24
  const int tg = xcd*25 + tsel;                // 0..199
  const int b = tg / 50, tile = tg % 50;
  const int th0 = (tile/5)*16, tw0 = (tile%5)*32;
  const int lane = threadIdx.x;
  __shared__ float wl[2][576];      // 12 row-slots x 48 cols, 2 bufs
  for (int i=lane; i<1152; i+=64) ((float*)wl)[i] = 0.f;
  float acc[2][8];
  #pragma unroll
  for (int k=0;k<2;k++)
    #pragma unroll
    for (int c2=0;c2<8;c2++) acc[k][c2]=0.f;
  const float* src = y64 + (size_t)b*1638400;
  // staging: 144 slots (12 rows x 12 float4); lane handles m = lane, lane+64, lane+128(<144)
  int sdst[3], soff[3];
  bool sok[3];
  #pragma unroll
  for (int j=0;j<3;j++){
    int m = lane + j*64;
    bool act = m < 144;
    int mm = act ? m : 0;
    int srow = mm/12, q = mm - srow*12;
    int dlt = srow + 3*(srow>=2) + (srow>=4) + (srow>=8) + 3*(srow>=10);  // {0,1,5,6,8,9,10,11,13,14,18,19}
    int gh = th0 - 5 + 2*wv + dlt, gw = tw0 - 8 + q*4;
    sok[j] = act && ((unsigned)gh < 160u) && ((unsigned)gw < 160u);
    soff[j] = gh*160 + gw;
    sdst[j] = srow*48 + q*4;
  }
  // prologue: stage ci=0 (OOB/inactive slots stay zero forever)
  #pragma unroll
  for (int j=0;j<3;j++)
    if (sok[j]) *(float4*)&wl[0][sdst[j]] = *(const float4*)(src + soff[j]);
  const int lrl = (lane >> 5) & 1, c = lane & 31;
  const int t0base = lrl*48 + c + 3;
  for (int ci=0; ci<64; ci++){
    float4 n0, n1, n2;
    if (ci < 63){
      const float* sN = src + (size_t)(ci+1)*25600;
      if (sok[0]) n0 = *(const float4*)(sN + soff[0]);
      if (sok[1]) n1 = *(const float4*)(sN + soff[1]);
      if (sok[2]) n2 = *(const float4*)(sN + soff[2]);
    }
    const float* Pb = wl[ci & 1];
    float t0[9], t1[9];
    {
      const float* pp = &Pb[t0base];
      t0[0]=pp[0];        t0[1]=pp[5];        t0[2]=pp[10];
      t0[3]=pp[2*48];     t0[4]=pp[2*48+5];   t0[5]=pp[2*48+10];
      t0[6]=pp[6*48];     t0[7]=pp[6*48+5];   t0[8]=pp[6*48+10];
      t1[0]=pp[4*48];     t1[1]=pp[4*48+5];   t1[2]=pp[4*48+10];
      t1[3]=pp[8*48];     t1[4]=pp[8*48+5];   t1[5]=pp[8*48+10];
      t1[6]=pp[10*48];    t1[7]=pp[10*48+5];  t1[8]=pp[10*48+10];
    }
    const float* wrow = w + ci*576 + cog*72;   // repacked: 72 contiguous dwords
    #pragma unroll
    for (int co=0;co<8;co++){
      const float* wp = wrow + co*9;
      float w0=wp[0],w1=wp[1],w2=wp[2],w3=wp[3],w4=wp[4],w5=wp[5],w6=wp[6],w7=wp[7],w8=wp[8];
      acc[0][co] += t0[0]*w0+t0[1]*w1+t0[2]*w2+t0[3]*w3+t0[4]*w4
                  + t0[5]*w5+t0[6]*w6+t0[7]*w7+t0[8]*w8;
      acc[1][co] += t1[0]*w0+t1[1]*w1+t1[2]*w2+t1[3]*w3+t1[4]*w4
                  + t1[5]*w5+t1[6]*w6+t1[7]*w7+t1[8]*w8;
    }
    if (ci < 63){
      float* Q = wl[(ci+1)&1];
      if (sok[0]) *(float4*)&Q[sdst[0]] = n0;
      if (sok[1]) *(float4*)&Q[sdst[1]] = n1;
      if (sok[2]) *(float4*)&Q[sdst[2]] = n2;
    }
  }
  #pragma unroll
  for (int k=0;k<2;k++){
    int h = th0 + 2*wv + lrl + k*8, wq = tw0 + c;
    #pragma unroll
    for (int co=0;co<8;co++){
      int cg = cog*8 + co;
      size_t base = ((size_t)(b*64+cg)*160 + h)*160 + wq;
      outp[base] = acc[k][co] + resid[base];
    }
  }
}

extern "C" void kernel_launch(void* const* d_in, const int* in_sizes, int n_in,
                              void* d_out, int out_size, void* d_ws, size_t ws_size,
                              hipStream_t stream){
  const float* x    = (const float*)d_in[0];
  const float* x1   = (const float*)d_in[1];
  const float* wspa = (const float*)d_in[2];
  const float* wang = (const float*)d_in[3];
  const float* we1  = (const float*)d_in[4];
  const float* we2  = (const float*)d_in[5];
  const float* al   = (const float*)d_in[6];
  const float* ga   = (const float*)d_in[7];
  const float* be   = (const float*)d_in[8];
  const float* wf1  = (const float*)d_in[9];
  const float* wf2  = (const float*)d_in[10];

  char* ws = (char*)d_ws;
  const size_t SLOT = 26214400;
  float* A  = (float*)(ws);          // MacPI buf (in-place residual chain)
  float* Bv = (float*)(ws +   SLOT); // B1 input / branchV / newB1
  float* T1 = (float*)(ws + 2*SLOT); // branchSpa -> y64 in-place
  float* T2 = (float*)(ws + 3*SLOT); // epiV tmp -> branchAng
  float* part = (float*)(ws + 4*SLOT);            // 4*64*16 f32 (16KB)
  float* Weff = (float*)(ws + 4*SLOT + 16384);    // 4*64*256 f32 (256KB)
  float* Wrep = (float*)(ws + 4*SLOT + 16384 + 262144);  // 3*4*36864 f32 (1.7MB)
  float* WspaR = Wrep;
  float* WangR = Wrep + 147456;
  float* Wf2R  = Wrep + 2*147456;
  float* D = (float*)d_out;          // A^T / branchH scratch; final output at the end

  k_wrep<<<1728,256,0,stream>>>(wspa, wang, wf2, Wrep);

  for (int i=0;i<4;i++){
    const float* Asrc  = (i==0) ? x  : (const float*)A;
    const float* B1src = (i==0) ? x1 : (const float*)Bv;
    k_permV<<<dim3(256,25),256,0,stream>>>(Asrc, D);                             // D = Asrc^T
    k_epi<<<1280,320,0,stream>>>(D, we1 + (size_t)i*61440, we2 + (size_t)i*20480, T2);   // epiV (tmp layout)
    k_spa<<<6400,64,0,stream>>>(B1src, WspaR + (size_t)i*36864, T1);
    k_permV<<<dim3(256,25),256,0,stream>>>(T2, Bv);                              // branchV
    k_ang<<<1024,320,0,stream>>>(Asrc, WangR + (size_t)i*36864, T2);
    k_epi<<<1280,320,0,stream>>>(Asrc, we1 + (size_t)i*61440, we2 + (size_t)i*20480, D); // branchH
    k_red<<<dim3(64,4),256,0,stream>>>(T1, T2, D, Bv, part);
    k_attW<<<4,256,0,stream>>>(part, al, ga, be, i, wf1 + (size_t)i*16384, Weff);
    k_fuse1<<<dim3(400,4),256,0,stream>>>(T1, T2, D, Bv, Weff, T1);
    if (i<3){
      k_fuse2<0><<<6400,64,0,stream>>>(T1, Asrc, Wf2R + (size_t)i*36864, A);
      k_permM<<<8192,256,0,stream>>>(A, Bv);
    } else {
      k_fuse2<1><<<6400,64,0,stream>>>(T1, Asrc, Wf2R + (size_t)i*36864, D);
    }
  }
}